// Round 6
// baseline (892.468 us; speedup 1.0000x reference)
//
#include <hip/hip_runtime.h>

#define B_  4
#define S_  1024
#define D_  1024
#define H_  16
#define DH  64
#define BS  4096   // B_*S_

typedef __bf16 bf16x8 __attribute__((ext_vector_type(8)));
typedef float  f32x4  __attribute__((ext_vector_type(4)));

__device__ __forceinline__ unsigned short f2bf(float f) {
    __bf16 b = (__bf16)f;
    return __builtin_bit_cast(unsigned short, b);
}
__device__ __forceinline__ float bf2f(unsigned short u) {
    return (float)__builtin_bit_cast(__bf16, u);
}
// async global->LDS, 16B/lane; LDS dest = wave-uniform base + lane*16
__device__ __forceinline__ void glds16(const void* g, void* l) {
    __builtin_amdgcn_global_load_lds((const __attribute__((address_space(1))) void*)g,
                                     (__attribute__((address_space(3))) void*)l, 16, 0, 0);
}

// ---------------- prep2: weight transp+hi/lo splits, Wvsh^T (padded) split, bvp ----------------
__global__ __launch_bounds__(256) void prep2(const float* __restrict__ Wq,
                                             const float* __restrict__ Wk,
                                             const float* __restrict__ Wo,
                                             const float* __restrict__ Wv,
                                             const float* __restrict__ bv,
                                             unsigned short* __restrict__ WqTh,
                                             unsigned short* __restrict__ WqTl,
                                             unsigned short* __restrict__ WkTh,
                                             unsigned short* __restrict__ WkTl,
                                             unsigned short* __restrict__ WoTh,
                                             unsigned short* __restrict__ WvTh,
                                             unsigned short* __restrict__ WvTl,
                                             float* __restrict__ bvp) {
    __shared__ float tile[32][33];
    int bid = blockIdx.x, tid = threadIdx.x;
    if (bid < 3072) {
        const float* W;
        unsigned short *Th, *Tl;
        int wantLo;
        if (bid < 1024)      { W = Wq; Th = WqTh; Tl = WqTl; wantLo = 1; }
        else if (bid < 2048) { W = Wk; Th = WkTh; Tl = WkTl; wantLo = 1; bid -= 1024; }
        else                 { W = Wo; Th = WoTh; Tl = nullptr; wantLo = 0; bid -= 2048; }
        int tn = bid & 31, tk = bid >> 5;
        int r = tid >> 3, c4 = (tid & 7) * 4;
        float4 v = *(const float4*)(W + (size_t)(tk * 32 + r) * D_ + tn * 32 + c4);
        tile[r][c4 + 0] = v.x;
        tile[r][c4 + 1] = v.y;
        tile[r][c4 + 2] = v.z;
        tile[r][c4 + 3] = v.w;
        __syncthreads();
        unsigned short hh[4], ll[4];
#pragma unroll
        for (int i = 0; i < 4; i++) {
            float f = tile[c4 + i][r];
            hh[i] = f2bf(f);
            ll[i] = f2bf(f - bf2f(hh[i]));
        }
        size_t off = (size_t)(tn * 32 + r) * D_ + tk * 32 + c4;
        *(uint2*)(Th + off) = make_uint2((unsigned)hh[0] | ((unsigned)hh[1] << 16),
                                         (unsigned)hh[2] | ((unsigned)hh[3] << 16));
        if (wantLo)
            *(uint2*)(Tl + off) = make_uint2((unsigned)ll[0] | ((unsigned)ll[1] << 16),
                                             (unsigned)ll[2] | ((unsigned)ll[3] << 16));
    } else if (bid < 3328) {
        // Wvsh^T rows 0..63: WvT[j][d] = mean_h Wv[d][h*64+j], hi/lo
        int e = (bid - 3072) * 256 + tid;      // 0..65535
        int d = e >> 6, j = e & 63;
        float s = 0.f;
#pragma unroll
        for (int hh = 0; hh < H_; hh++) s += Wv[(size_t)d * D_ + hh * DH + j];
        s *= (1.f / 16.f);
        unsigned short hi = f2bf(s);
        WvTh[(size_t)j * D_ + d] = hi;
        WvTl[(size_t)j * D_ + d] = f2bf(s - bf2f(hi));
        if (bid == 3072 && tid < 128) {
            float sb = 0.f;
            if (tid < 64) {
#pragma unroll
                for (int hh = 0; hh < H_; hh++) sb += bv[hh * DH + tid];
                sb *= (1.f / 16.f);
            }
            bvp[tid] = sb;
        }
    } else {
        // zero-pad rows 64..127 of Wvsh^T
        int e = (bid - 3328) * 256 + tid;      // 0..65535
        int row = 64 + (e >> 10), col = e & 1023;
        WvTh[(size_t)row * D_ + col] = 0;
        WvTl[(size_t)row * D_ + col] = 0;
    }
}

// ---------------- projg: fused Q/K/v_shared projection, 128x128 tile, hilo, B via glds ----------------
// grid (17, 32): bn<8 -> Q cols, bn<16 -> K cols, bn==16 -> v_shared (padded tile)
__global__ __launch_bounds__(256) void projg(const float* __restrict__ x,
                                             const unsigned short* __restrict__ WqTh, const unsigned short* __restrict__ WqTl,
                                             const unsigned short* __restrict__ WkTh, const unsigned short* __restrict__ WkTl,
                                             const unsigned short* __restrict__ WvTh, const unsigned short* __restrict__ WvTl,
                                             const float* __restrict__ bq, const float* __restrict__ bk,
                                             const float* __restrict__ bvp,
                                             unsigned short* __restrict__ qh, unsigned short* __restrict__ ql,
                                             unsigned short* __restrict__ kh, unsigned short* __restrict__ kl,
                                             float* __restrict__ vshb) {
    __shared__ unsigned short AhS[128 * 32];
    __shared__ unsigned short AlS[128 * 32];
    __shared__ unsigned short BhS[128 * 32];
    __shared__ unsigned short BlS[128 * 32];

    int tid = threadIdx.x, w = tid >> 6, lane = tid & 63;
    int m16 = lane & 15, qd = lane >> 4;
    int bn = blockIdx.x, bm = blockIdx.y;

    const unsigned short *Bh, *Bl;
    const float* bias;
    int mode;
    if (bn < 8)       { Bh = WqTh + (size_t)bn * 128 * D_;       Bl = WqTl + (size_t)bn * 128 * D_;       bias = bq + bn * 128;       mode = 0; }
    else if (bn < 16) { Bh = WkTh + (size_t)(bn - 8) * 128 * D_; Bl = WkTl + (size_t)(bn - 8) * 128 * D_; bias = bk + (bn - 8) * 128; mode = 1; }
    else              { Bh = WvTh; Bl = WvTl; bias = bvp; mode = 2; }

    int l4 = lane >> 2, c8 = (lane & 3) * 8;     // staging: row offset, k offset (elems)
    int rh = (w >> 1) * 64, chh = (w & 1) * 64;  // wave quadrant

    f32x4 acc[4][4];
#pragma unroll
    for (int it = 0; it < 4; it++)
#pragma unroll
        for (int jt = 0; jt < 4; jt++) acc[it][jt] = (f32x4){0.f, 0.f, 0.f, 0.f};

    int ra = tid >> 1, ca = (tid & 1) * 16;      // A staging: 16 floats/thread

    for (int k0 = 0; k0 < D_; k0 += 32) {
        // A: fp32 -> bf16 hi/lo (issue loads before barrier for overlap)
        const float* ax = x + (size_t)(bm * 128 + ra) * D_ + k0 + ca;
        float4 f0 = *(const float4*)(ax + 0);
        float4 f1 = *(const float4*)(ax + 4);
        float4 f2 = *(const float4*)(ax + 8);
        float4 f3 = *(const float4*)(ax + 12);
        __syncthreads();
        {
            float vv[16] = {f0.x, f0.y, f0.z, f0.w, f1.x, f1.y, f1.z, f1.w,
                            f2.x, f2.y, f2.z, f2.w, f3.x, f3.y, f3.z, f3.w};
            unsigned int hw[8], lw[8];
#pragma unroll
            for (int i = 0; i < 8; i++) {
                unsigned short h0 = f2bf(vv[2 * i]), h1 = f2bf(vv[2 * i + 1]);
                unsigned short l0 = f2bf(vv[2 * i] - bf2f(h0));
                unsigned short l1 = f2bf(vv[2 * i + 1] - bf2f(h1));
                hw[i] = (unsigned)h0 | ((unsigned)h1 << 16);
                lw[i] = (unsigned)l0 | ((unsigned)l1 << 16);
            }
            char* ah = (char*)AhS + ra * 64 + ca * 2;
            char* al = (char*)AlS + ra * 64 + ca * 2;
            *(uint4*)(ah + 0)  = make_uint4(hw[0], hw[1], hw[2], hw[3]);
            *(uint4*)(ah + 16) = make_uint4(hw[4], hw[5], hw[6], hw[7]);
            *(uint4*)(al + 0)  = make_uint4(lw[0], lw[1], lw[2], lw[3]);
            *(uint4*)(al + 16) = make_uint4(lw[4], lw[5], lw[6], lw[7]);
        }
        // B: async glds, wave w stages tile rows w*32..w*32+32
        {
            const unsigned short* gbh = Bh + (size_t)(w * 32 + l4) * D_ + k0 + c8;
            const unsigned short* gbl = Bl + (size_t)(w * 32 + l4) * D_ + k0 + c8;
            glds16(gbh,                     (char*)BhS + w * 2048);
            glds16(gbh + (size_t)16 * D_,   (char*)BhS + w * 2048 + 1024);
            glds16(gbl,                     (char*)BlS + w * 2048);
            glds16(gbl + (size_t)16 * D_,   (char*)BlS + w * 2048 + 1024);
        }
        __syncthreads();
        bf16x8 ah[4], al[4], bh[4], bl[4];
#pragma unroll
        for (int it = 0; it < 4; it++) {
            ah[it] = *(const bf16x8*)((char*)AhS + (rh + it * 16 + m16) * 64 + qd * 16);
            al[it] = *(const bf16x8*)((char*)AlS + (rh + it * 16 + m16) * 64 + qd * 16);
        }
#pragma unroll
        for (int jt = 0; jt < 4; jt++) {
            bh[jt] = *(const bf16x8*)((char*)BhS + (chh + jt * 16 + m16) * 64 + qd * 16);
            bl[jt] = *(const bf16x8*)((char*)BlS + (chh + jt * 16 + m16) * 64 + qd * 16);
        }
#pragma unroll
        for (int it = 0; it < 4; it++)
#pragma unroll
            for (int jt = 0; jt < 4; jt++) {
                acc[it][jt] = __builtin_amdgcn_mfma_f32_16x16x32_bf16(ah[it], bh[jt], acc[it][jt], 0, 0, 0);
                acc[it][jt] = __builtin_amdgcn_mfma_f32_16x16x32_bf16(ah[it], bl[jt], acc[it][jt], 0, 0, 0);
                acc[it][jt] = __builtin_amdgcn_mfma_f32_16x16x32_bf16(al[it], bh[jt], acc[it][jt], 0, 0, 0);
            }
    }
#pragma unroll
    for (int it = 0; it < 4; it++)
#pragma unroll
        for (int jt = 0; jt < 4; jt++)
#pragma unroll
            for (int r = 0; r < 4; r++) {
                int R = bm * 128 + rh + it * 16 + qd * 4 + r;
                int c = chh + jt * 16 + m16;
                float v = acc[it][jt][r] + bias[c];
                if (mode == 0) {
                    v *= 0.125f;
                    unsigned short h0 = f2bf(v);
                    qh[(size_t)R * D_ + bn * 128 + c] = h0;
                    ql[(size_t)R * D_ + bn * 128 + c] = f2bf(v - bf2f(h0));
                } else if (mode == 1) {
                    unsigned short h0 = f2bf(v);
                    kh[(size_t)R * D_ + (bn - 8) * 128 + c] = h0;
                    kl[(size_t)R * D_ + (bn - 8) * 128 + c] = f2bf(v - bf2f(h0));
                } else {
                    if (c < 64) vshb[(size_t)R * 64 + c] = v;
                }
            }
}

// ---------------- outg: x_out = och @ Wo + bo, 64x64 tile (4 blocks/CU), bf16 single, all glds ----------------
__global__ __launch_bounds__(256) void outg(const unsigned short* __restrict__ A,
                                            const unsigned short* __restrict__ Bh,
                                            const float* __restrict__ bias,
                                            float* __restrict__ C) {
    __shared__ unsigned short AhS[64 * 32];
    __shared__ unsigned short BhS[64 * 32];

    int tid = threadIdx.x, w = tid >> 6, lane = tid & 63;
    int m16 = lane & 15, qd = lane >> 4;
    int bn = blockIdx.x, bm = blockIdx.y;
    int l4 = lane >> 2, c8 = (lane & 3) * 8;
    int rh = (w >> 1) * 32, chh = (w & 1) * 32;

    f32x4 acc[2][2];
#pragma unroll
    for (int it = 0; it < 2; it++)
#pragma unroll
        for (int jt = 0; jt < 2; jt++) acc[it][jt] = (f32x4){0.f, 0.f, 0.f, 0.f};

    for (int k0 = 0; k0 < D_; k0 += 32) {
        __syncthreads();
        {
            const unsigned short* ga = A + (size_t)(bm * 64 + w * 16 + l4) * D_ + k0 + c8;
            glds16(ga, (char*)AhS + w * 1024);
            const unsigned short* gb = Bh + (size_t)(bn * 64 + w * 16 + l4) * D_ + k0 + c8;
            glds16(gb, (char*)BhS + w * 1024);
        }
        __syncthreads();
        bf16x8 ah[2], bh[2];
#pragma unroll
        for (int it = 0; it < 2; it++)
            ah[it] = *(const bf16x8*)((char*)AhS + (rh + it * 16 + m16) * 64 + qd * 16);
#pragma unroll
        for (int jt = 0; jt < 2; jt++)
            bh[jt] = *(const bf16x8*)((char*)BhS + (chh + jt * 16 + m16) * 64 + qd * 16);
#pragma unroll
        for (int it = 0; it < 2; it++)
#pragma unroll
            for (int jt = 0; jt < 2; jt++)
                acc[it][jt] = __builtin_amdgcn_mfma_f32_16x16x32_bf16(ah[it], bh[jt], acc[it][jt], 0, 0, 0);
    }
#pragma unroll
    for (int it = 0; it < 2; it++)
#pragma unroll
        for (int jt = 0; jt < 2; jt++)
#pragma unroll
            for (int r = 0; r < 4; r++) {
                int R = bm * 64 + rh + it * 16 + qd * 4 + r;
                int cc = bn * 64 + chh + jt * 16 + m16;
                C[(size_t)R * D_ + cc] = acc[it][jt][r] + bias[cc];
            }
}

// ---------------- fused attention v13: two-pass recompute QK for occupancy ----------------
// Evidence: v10/v12 stuck at 143us, occupancy 34%, all pipes idle -> TLP-starved.
// Both caps bind at 16 waves/CU: LDS 34KB (4 blocks) AND VGPR+AGPR ~128 (Cfr[16]=64 AGPR).
// v13 removes the Cfr array entirely: pass 1 computes each 16-key tile's scores into a
// single f32x4 and folds a running row-max; pass 2 RECOMPUTES the bit-identical 6-MFMA
// chain (MFMA util was 7% - capacity is free) and scatters candidates immediately.
// Staging: single 4KB buffer/wave (KST 16KB). LDS ~22KB, regs ~60 -> 6 blocks/CU
// (launch_bounds(256,6)), 24 waves/CU. Overflow path (statistically never) re-converges
// tau via additional recompute passes. slotV/slotI alias candV (all candV/candI reads
// pulled into registers before the pre-slot barrier).
#define CCAP 48
__global__ __launch_bounds__(256, 6) void attn8(const unsigned short* __restrict__ qh,
                                                const unsigned short* __restrict__ ql,
                                                const unsigned short* __restrict__ kh,
                                                const unsigned short* __restrict__ kl,
                                                const float* __restrict__ vsh,
                                                unsigned short* __restrict__ och,
                                                unsigned short* __restrict__ sidx,
                                                unsigned short* __restrict__ sval,
                                                int* __restrict__ scnt) {
    __shared__ __align__(16) char KST[16384];      // 4 waves x 4KB single buffer (hi 2KB, lo 2KB)
    __shared__ __align__(16) float candVS[16][CCAP];  // 3072 B (NOT aliased: live during pass-2 staging)
    __shared__ short candIS[16][CCAP];                // 1536 B
    __shared__ float smM[4][16];
    __shared__ float smS[4][16], smC[4][16];
    __shared__ float tau0s[16];
    __shared__ float taus[16];
    __shared__ int   ccnt[16];
    __shared__ int   ovfAny;
    __shared__ int   scnt16[16];

    // slots alias candVS: all candVS/candIS reads are register-preloaded before the
    // barrier that precedes any slot write (both paths).
    float (*slotV)[16] = (float (*)[16])((char*)candVS);          // 1024 B
    short (*slotI)[16] = (short (*)[16])((char*)candVS + 1024);   //  512 B

    int tid = threadIdx.x, w = tid >> 6, lane = tid & 63;
    int m16 = lane & 15, qd = lane >> 4;

    // qt-major decode: same-XCD consecutive blocks share (bb,h), walk qt.
    int bid = blockIdx.x;
    int xcd = bid & 7;
    int j   = bid >> 3;                 // 0..511
    int bh  = ((j >> 6) << 3) | xcd;    // 0..63
    int qt  = j & 63;
    int bb  = bh >> 4, h = bh & 15;
    int row0g = bb * S_ + qt * 16;
    int kbase = bb * S_;

    // Q fragments (direct global, once)
    bf16x8 aH[2], aL[2];
#pragma unroll
    for (int c = 0; c < 2; c++) {
        size_t off = (size_t)(row0g + m16) * D_ + h * DH + c * 32 + qd * 8;
        aH[c] = *(const bf16x8*)(qh + off);
        aL[c] = *(const bf16x8*)(ql + off);
    }

    // staging source: lane l covers row (l>>3), swizzled chunk (l&7)^(l>>3)
    char* myK = KST + w * 4096;
    int sr = lane >> 3;
    int sc = (lane & 7) ^ sr;
    const unsigned short* ksh = kh + (size_t)(kbase + w * 256 + sr) * D_ + h * DH + sc * 8;
    const unsigned short* ksl = kl + (size_t)(kbase + w * 256 + sr) * D_ + h * DH + sc * 8;

#define STAGE_K(t) do {                                         \
        size_t o_ = (size_t)(t) * 16 * D_;                      \
        glds16(ksh + o_,                  myK);                 \
        glds16(ksh + o_ + (size_t)8 * D_, myK + 1024);          \
        glds16(ksl + o_,                  myK + 2048);          \
        glds16(ksl + o_ + (size_t)8 * D_, myK + 3072);          \
    } while (0)

    // fragment read offsets (swizzled): chunk c*4+qd, row m16
    int sw0 = m16 * 128 + (((qd    ) ^ (m16 & 7)) << 4);
    int sw1 = m16 * 128 + (((4 + qd) ^ (m16 & 7)) << 4);

    // per-tile score compute: waits tile in LDS, reads frags, drains reads, optionally
    // stages next tile into the SAME buffer (safe: reads drained), then 6 MFMAs.
#define QK_TILE(t, STAGE_NEXT, NEXT_T, a)                                   \
    {                                                                       \
        asm volatile("s_waitcnt vmcnt(0)" ::: "memory");                    \
        __builtin_amdgcn_sched_barrier(0);                                  \
        bf16x8 bfh0 = *(const bf16x8*)(myK + sw0);                          \
        bf16x8 bfh1 = *(const bf16x8*)(myK + sw1);                          \
        bf16x8 bfl0 = *(const bf16x8*)(myK + 2048 + sw0);                   \
        bf16x8 bfl1 = *(const bf16x8*)(myK + 2048 + sw1);                   \
        asm volatile("s_waitcnt lgkmcnt(0)" ::: "memory");                  \
        __builtin_amdgcn_sched_barrier(0);                                  \
        if (STAGE_NEXT) STAGE_K(NEXT_T);                                    \
        a = (f32x4){0.f, 0.f, 0.f, 0.f};                                    \
        __builtin_amdgcn_s_setprio(1);                                      \
        a = __builtin_amdgcn_mfma_f32_16x16x32_bf16(aH[0], bfh0, a, 0, 0, 0); \
        a = __builtin_amdgcn_mfma_f32_16x16x32_bf16(aH[1], bfh1, a, 0, 0, 0); \
        a = __builtin_amdgcn_mfma_f32_16x16x32_bf16(aH[0], bfl0, a, 0, 0, 0); \
        a = __builtin_amdgcn_mfma_f32_16x16x32_bf16(aH[1], bfl1, a, 0, 0, 0); \
        a = __builtin_amdgcn_mfma_f32_16x16x32_bf16(aL[0], bfh0, a, 0, 0, 0); \
        a = __builtin_amdgcn_mfma_f32_16x16x32_bf16(aL[1], bfh1, a, 0, 0, 0); \
        __builtin_amdgcn_s_setprio(0);                                      \
    }

    // ---- PASS 1: row max ----
    float mxr[4];
#pragma unroll
    for (int r = 0; r < 4; r++) mxr[r] = -3.0e38f;
    STAGE_K(0);
#pragma unroll
    for (int t = 0; t < 16; t++) {
        f32x4 a;
        QK_TILE(t, t < 15, t + 1, a);
#pragma unroll
        for (int r = 0; r < 4; r++) mxr[r] = fmaxf(mxr[r], a[r]);
    }
    STAGE_K(0);   // prefetch pass-2 tile 0 across the barrier section (wave-private buffer)

#pragma unroll
    for (int off = 8; off >= 1; off >>= 1)
#pragma unroll
        for (int r = 0; r < 4; r++) mxr[r] = fmaxf(mxr[r], __shfl_xor(mxr[r], off, 16));
    if (m16 == 0)
#pragma unroll
        for (int r = 0; r < 4; r++) smM[w][qd * 4 + r] = mxr[r];
    if (tid < 16) ccnt[tid] = 0;
    if (tid == 0) ovfAny = 0;
    __syncthreads();
    if (tid < 16)
        tau0s[tid] = fmaxf(fmaxf(smM[0][tid], smM[1][tid]), fmaxf(smM[2][tid], smM[3][tid])) - 1.0f;
    __syncthreads();

    float t0r[4];
#pragma unroll
    for (int r = 0; r < 4; r++) t0r[r] = tau0s[qd * 4 + r];

    // ---- PASS 2: recompute (bit-identical z) + candidate scatter ----
#pragma unroll
    for (int t = 0; t < 16; t++) {
        f32x4 a;
        QK_TILE(t, t < 15, t + 1, a);
#pragma unroll
        for (int r = 0; r < 4; r++) {
            float z = a[r];
            int row = qd * 4 + r;
            if (z > t0r[r]) {
                int pos = atomicAdd(&ccnt[row], 1);
                if (pos < CCAP) {
                    candVS[row][pos] = z;
                    candIS[row][pos] = (short)(w * 256 + t * 16 + m16);
                }
            }
        }
    }
    __syncthreads();
    if (tid < 16 && ccnt[tid] > CCAP) ovfAny = 1;

    int prow = tid >> 4, pc = tid & 15;
    int nc = ccnt[prow];
    float tau = tau0s[prow];
    float z0 = -3.0e38f, z1 = -3.0e38f, z2 = -3.0e38f;
    // preload candidate indices into regs (slots alias candVS; no LDS reads after barrier)
    short i0r = candIS[prow][pc];
    short i1r = candIS[prow][pc + 16];
    short i2r = candIS[prow][pc + 32];
    if (nc <= CCAP) {
        z0 = (pc < nc)      ? candVS[prow][pc]      : -3.0e38f;
        z1 = (pc + 16 < nc) ? candVS[prow][pc + 16] : -3.0e38f;
        z2 = (pc + 32 < nc) ? candVS[prow][pc + 32] : -3.0e38f;
        for (int it = 0; it < CCAP; it++) {
            float s = 0.f, c = 0.f;
            if (z0 > tau) { s += z0; c += 1.f; }
            if (z1 > tau) { s += z1; c += 1.f; }
            if (z2 > tau) { s += z2; c += 1.f; }
#pragma unroll
            for (int off = 8; off >= 1; off >>= 1) {
                s += __shfl_xor(s, off, 16);
                c += __shfl_xor(c, off, 16);
            }
            float tnew = (s - 1.f) / c;
            if (tnew > tau) tau = tnew; else break;
        }
    }
    if (pc == 0) taus[prow] = tau;
    if (tid < 16) scnt16[tid] = 0;
    __syncthreads();

    if (!ovfAny) {
        if (z0 > tau) {
            int sl = atomicAdd(&scnt16[prow], 1);
            if (sl < 16) { slotI[prow][sl] = i0r; slotV[prow][sl] = z0 - tau; }
        }
        if (z1 > tau) {
            int sl = atomicAdd(&scnt16[prow], 1);
            if (sl < 16) { slotI[prow][sl] = i1r; slotV[prow][sl] = z1 - tau; }
        }
        if (z2 > tau) {
            int sl = atomicAdd(&scnt16[prow], 1);
            if (sl < 16) { slotI[prow][sl] = i2r; slotV[prow][sl] = z2 - tau; }
        }
        __syncthreads();
    } else {
        // overflow (rare): converge tau by full recompute passes
        for (int it = 0; it < 64; it++) {
            float s[4], c[4], tsr[4];
#pragma unroll
            for (int r = 0; r < 4; r++) { s[r] = 0.f; c[r] = 0.f; tsr[r] = taus[qd * 4 + r]; }
            STAGE_K(0);
#pragma unroll
            for (int t = 0; t < 16; t++) {
                f32x4 a;
                QK_TILE(t, t < 15, t + 1, a);
#pragma unroll
                for (int r = 0; r < 4; r++) {
                    float z = a[r];
                    if (z > tsr[r]) { s[r] += z; c[r] += 1.f; }
                }
            }
#pragma unroll
            for (int off = 8; off >= 1; off >>= 1)
#pragma unroll
                for (int r = 0; r < 4; r++) {
                    s[r] += __shfl_xor(s[r], off, 16);
                    c[r] += __shfl_xor(c[r], off, 16);
                }
            if (m16 == 0)
#pragma unroll
                for (int r = 0; r < 4; r++) {
                    smS[w][qd * 4 + r] = s[r];
                    smC[w][qd * 4 + r] = c[r];
                }
            __syncthreads();
            int done = 1;
            if (tid < 16) {
                float S = smS[0][tid] + smS[1][tid] + smS[2][tid] + smS[3][tid];
                float C = smC[0][tid] + smC[1][tid] + smC[2][tid] + smC[3][tid];
                float tnew = (S - 1.f) / C;
                if (C > 0.f && tnew > taus[tid]) { taus[tid] = tnew; done = 0; }
            }
            if (__syncthreads_and(done)) break;
        }
        // final scatter pass with converged taus (candVS dead -> slot alias safe)
        float tfr[4];
#pragma unroll
        for (int r = 0; r < 4; r++) tfr[r] = taus[qd * 4 + r];
        STAGE_K(0);
#pragma unroll
        for (int t = 0; t < 16; t++) {
            f32x4 a;
            QK_TILE(t, t < 15, t + 1, a);
#pragma unroll
            for (int r = 0; r < 4; r++) {
                int row = qd * 4 + r;
                float p = a[r] - tfr[r];
                if (p > 0.f) {
                    int sl = atomicAdd(&scnt16[row], 1);
                    if (sl < 16) {
                        slotI[row][sl] = (short)(w * 256 + t * 16 + m16);
                        slotV[row][sl] = p;
                    }
                }
            }
        }
        __syncthreads();
    }
#undef QK_TILE
#undef STAGE_K

    int nsl = min(scnt16[prow], 16);
    // ---- PV batch-gather: wide LDS reads, then all 16 V-loads independent ----
    f32x4 v0 = *(const f32x4*)&slotV[prow][0];
    f32x4 v1 = *(const f32x4*)&slotV[prow][4];
    f32x4 v2 = *(const f32x4*)&slotV[prow][8];
    f32x4 v3 = *(const f32x4*)&slotV[prow][12];
    const uint4* sIv = (const uint4*)&slotI[prow][0];
    uint4 i0 = sIv[0], i1 = sIv[1];
    float pA[16] = {v0[0], v0[1], v0[2], v0[3], v1[0], v1[1], v1[2], v1[3],
                    v2[0], v2[1], v2[2], v2[3], v3[0], v3[1], v3[2], v3[3]};
    unsigned wI[8] = {i0.x, i0.y, i0.z, i0.w, i1.x, i1.y, i1.z, i1.w};
    float4 accq = make_float4(0.f, 0.f, 0.f, 0.f);
#pragma unroll
    for (int sl = 0; sl < 16; sl++) {
        float p = (sl < nsl) ? pA[sl] : 0.f;
        int key = (int)((wI[sl >> 1] >> ((sl & 1) * 16)) & 1023u);
        float4 vv = *(const float4*)(vsh + (size_t)(kbase + key) * DH + pc * 4);
        accq.x += p * vv.x;
        accq.y += p * vv.y;
        accq.z += p * vv.z;
        accq.w += p * vv.w;
    }
    {
        unsigned short b0 = f2bf(accq.x), b1 = f2bf(accq.y), b2 = f2bf(accq.z), b3 = f2bf(accq.w);
        *(uint2*)(och + (size_t)(row0g + prow) * D_ + h * DH + pc * 4) =
            make_uint2((unsigned)b0 | ((unsigned)b1 << 16), (unsigned)b2 | ((unsigned)b3 << 16));
    }
    {
        size_t base = ((size_t)(row0g + prow) * H_ + h) * 16;
        if (pc == 0) scnt[(row0g + prow) * H_ + h] = nsl;
        if (pc < nsl) {
            sidx[base + pc] = (unsigned short)slotI[prow][pc];
            sval[base + pc] = f2bf(slotV[prow][pc]);
        }
    }
}

// ---------------- avg_attention: per-row reduction over 16 heads ----------------
__global__ __launch_bounds__(256) void avg_reduce(const unsigned short* __restrict__ sidx,
                                                  const unsigned short* __restrict__ sval,
                                                  const int* __restrict__ scnt,
                                                  float* __restrict__ avg) {
    __shared__ float accv[1024];
    int tid = threadIdx.x;
    int grow = blockIdx.x;
    for (int i = tid; i < 1024; i += 256) accv[i] = 0.f;
    __syncthreads();
    int h = tid >> 4, sl = tid & 15;
    int n = scnt[grow * H_ + h];
    if (sl < n) {
        size_t base = ((size_t)grow * H_ + h) * 16;
        int idx = sidx[base + sl];
        float v = bf2f(sval[base + sl]);
        atomicAdd(&accv[idx], v);
    }
    __syncthreads();
    float* dst = avg + (size_t)grow * S_;
    for (int i = tid; i < 256; i += 256) {
        float4 o;
        o.x = accv[i * 4 + 0] * 0.0625f;
        o.y = accv[i * 4 + 1] * 0.0625f;
        o.z = accv[i * 4 + 2] * 0.0625f;
        o.w = accv[i * 4 + 3] * 0.0625f;
        *(float4*)(dst + i * 4) = o;
    }
}

extern "C" void kernel_launch(void* const* d_in, const int* in_sizes, int n_in,
                              void* d_out, int out_size, void* d_ws, size_t ws_size,
                              hipStream_t stream) {
    const float* x  = (const float*)d_in[0];
    const float* Wq = (const float*)d_in[1];
    const float* bq = (const float*)d_in[2];
    const float* Wk = (const float*)d_in[3];
    const float* bk = (const float*)d_in[4];
    const float* Wv = (const float*)d_in[5];
    const float* bv = (const float*)d_in[6];
    const float* Wo = (const float*)d_in[7];
    const float* bo = (const float*)d_in[8];

    float* xout = (float*)d_out;                   // (B,S,D)
    float* avg  = xout + (size_t)BS * D_;          // (B,S,S)

    char* ws = (char*)d_ws;
    unsigned short* qhB  = (unsigned short*)(ws + 0);               // 8 MB
    unsigned short* qlB  = (unsigned short*)(ws + (8u << 20));      // 8 MB
    unsigned short* khB  = (unsigned short*)(ws + (16u << 20));     // 8 MB
    unsigned short* klB  = (unsigned short*)(ws + (24u << 20));     // 8 MB
    unsigned short* WqTh = (unsigned short*)(ws + (32u << 20));     // 2 MB
    unsigned short* WqTl = (unsigned short*)(ws + (34u << 20));     // 2 MB
    unsigned short* WkTh = (unsigned short*)(ws + (36u << 20));     // 2 MB
    unsigned short* WkTl = (unsigned short*)(ws + (38u << 20));     // 2 MB
    unsigned short* ochB = WqTh;                                    // alias 32..40 MB (dead after projg)
    unsigned short* WoTh = (unsigned short*)(ws + (40u << 20));     // 2 MB
    unsigned short* WvTh = (unsigned short*)(ws + (42u << 20));     // 256 KB (128x1024 bf16)
    unsigned short* WvTl = (unsigned short*)(ws + (42u << 20) + (256u << 10));  // 256 KB
    float* bvp = (float*)(ws + (42u << 20) + (512u << 10));         // 512 B
    float* vshb = (float*)(ws + (43u << 20));                       // 1 MB
    unsigned short* sidx = (unsigned short*)(ws + (44u << 20));     // 2 MB
    unsigned short* sval = (unsigned short*)(ws + (46u << 20));     // 2 MB
    int* scnt = (int*)(ws + (48u << 20));                           // 256 KB

    prep2<<<3584, 256, 0, stream>>>(Wq, Wk, Wo, Wv, bv, WqTh, WqTl, WkTh, WkTl, WoTh, WvTh, WvTl, bvp);
    projg<<<dim3(17, 32), 256, 0, stream>>>(x, WqTh, WqTl, WkTh, WkTl, WvTh, WvTl,
                                            bq, bk, bvp, qhB, qlB, khB, klB, vshb);
    attn8<<<4096, 256, 0, stream>>>(qhB, qlB, khB, klB, vshb, ochB, sidx, sval, scnt);
    avg_reduce<<<4096, 256, 0, stream>>>(sidx, sval, scnt, avg);
    outg<<<dim3(16, 64), 256, 0, stream>>>(ochB, WoTh, bo, xout);
}

// Round 7
// 348.587 us; speedup vs baseline: 2.5602x; 2.5602x over previous
//
#include <hip/hip_runtime.h>

#define B_  4
#define S_  1024
#define D_  1024
#define H_  16
#define DH  64
#define BS  4096   // B_*S_

typedef __bf16 bf16x8 __attribute__((ext_vector_type(8)));
typedef float  f32x4  __attribute__((ext_vector_type(4)));

__device__ __forceinline__ unsigned short f2bf(float f) {
    __bf16 b = (__bf16)f;
    return __builtin_bit_cast(unsigned short, b);
}
__device__ __forceinline__ float bf2f(unsigned short u) {
    return (float)__builtin_bit_cast(__bf16, u);
}
// async global->LDS, 16B/lane; LDS dest = wave-uniform base + lane*16
__device__ __forceinline__ void glds16(const void* g, void* l) {
    __builtin_amdgcn_global_load_lds((const __attribute__((address_space(1))) void*)g,
                                     (__attribute__((address_space(3))) void*)l, 16, 0, 0);
}

// ---------------- prep2: weight transp+hi/lo splits, Wvsh^T (padded) split, bvp, avg zero ----------------
// grid 7680: bid<3072 transpose, 3072..3327 Wvsh^T, 3328..3583 pad, 3584..7679 zero avg (16MB)
__global__ __launch_bounds__(256) void prep2(const float* __restrict__ Wq,
                                             const float* __restrict__ Wk,
                                             const float* __restrict__ Wo,
                                             const float* __restrict__ Wv,
                                             const float* __restrict__ bv,
                                             unsigned short* __restrict__ WqTh,
                                             unsigned short* __restrict__ WqTl,
                                             unsigned short* __restrict__ WkTh,
                                             unsigned short* __restrict__ WkTl,
                                             unsigned short* __restrict__ WoTh,
                                             unsigned short* __restrict__ WvTh,
                                             unsigned short* __restrict__ WvTl,
                                             float* __restrict__ bvp,
                                             float* __restrict__ avg) {
    __shared__ float tile[32][33];
    int bid = blockIdx.x, tid = threadIdx.x;
    if (bid < 3072) {
        const float* W;
        unsigned short *Th, *Tl;
        int wantLo;
        if (bid < 1024)      { W = Wq; Th = WqTh; Tl = WqTl; wantLo = 1; }
        else if (bid < 2048) { W = Wk; Th = WkTh; Tl = WkTl; wantLo = 1; bid -= 1024; }
        else                 { W = Wo; Th = WoTh; Tl = nullptr; wantLo = 0; bid -= 2048; }
        int tn = bid & 31, tk = bid >> 5;
        int r = tid >> 3, c4 = (tid & 7) * 4;
        float4 v = *(const float4*)(W + (size_t)(tk * 32 + r) * D_ + tn * 32 + c4);
        tile[r][c4 + 0] = v.x;
        tile[r][c4 + 1] = v.y;
        tile[r][c4 + 2] = v.z;
        tile[r][c4 + 3] = v.w;
        __syncthreads();
        unsigned short hh[4], ll[4];
#pragma unroll
        for (int i = 0; i < 4; i++) {
            float f = tile[c4 + i][r];
            hh[i] = f2bf(f);
            ll[i] = f2bf(f - bf2f(hh[i]));
        }
        size_t off = (size_t)(tn * 32 + r) * D_ + tk * 32 + c4;
        *(uint2*)(Th + off) = make_uint2((unsigned)hh[0] | ((unsigned)hh[1] << 16),
                                         (unsigned)hh[2] | ((unsigned)hh[3] << 16));
        if (wantLo)
            *(uint2*)(Tl + off) = make_uint2((unsigned)ll[0] | ((unsigned)ll[1] << 16),
                                             (unsigned)ll[2] | ((unsigned)ll[3] << 16));
    } else if (bid < 3328) {
        // Wvsh^T rows 0..63: WvT[j][d] = mean_h Wv[d][h*64+j], hi/lo
        int e = (bid - 3072) * 256 + tid;      // 0..65535
        int d = e >> 6, j = e & 63;
        float s = 0.f;
#pragma unroll
        for (int hh = 0; hh < H_; hh++) s += Wv[(size_t)d * D_ + hh * DH + j];
        s *= (1.f / 16.f);
        unsigned short hi = f2bf(s);
        WvTh[(size_t)j * D_ + d] = hi;
        WvTl[(size_t)j * D_ + d] = f2bf(s - bf2f(hi));
        if (bid == 3072 && tid < 128) {
            float sb = 0.f;
            if (tid < 64) {
#pragma unroll
                for (int hh = 0; hh < H_; hh++) sb += bv[hh * DH + tid];
                sb *= (1.f / 16.f);
            }
            bvp[tid] = sb;
        }
    } else if (bid < 3584) {
        // zero-pad rows 64..127 of Wvsh^T
        int e = (bid - 3328) * 256 + tid;      // 0..65535
        int row = 64 + (e >> 10), col = e & 1023;
        WvTh[(size_t)row * D_ + col] = 0;
        WvTl[(size_t)row * D_ + col] = 0;
    } else {
        // zero avg (B,S,S) = 4M floats: 4096 blocks x 256 threads x float4
        int e = (bid - 3584) * 256 + tid;      // 0..1048575
        *(float4*)(avg + (size_t)e * 4) = make_float4(0.f, 0.f, 0.f, 0.f);
    }
}

// ---------------- projg: fused Q/K/v_shared projection, 128x128 tile, hilo, B via glds ----------------
// grid (17, 32): bn<8 -> Q cols, bn<16 -> K cols, bn==16 -> v_shared (padded tile)
__global__ __launch_bounds__(256) void projg(const float* __restrict__ x,
                                             const unsigned short* __restrict__ WqTh, const unsigned short* __restrict__ WqTl,
                                             const unsigned short* __restrict__ WkTh, const unsigned short* __restrict__ WkTl,
                                             const unsigned short* __restrict__ WvTh, const unsigned short* __restrict__ WvTl,
                                             const float* __restrict__ bq, const float* __restrict__ bk,
                                             const float* __restrict__ bvp,
                                             unsigned short* __restrict__ qh, unsigned short* __restrict__ ql,
                                             unsigned short* __restrict__ kh, unsigned short* __restrict__ kl,
                                             float* __restrict__ vshb) {
    __shared__ unsigned short AhS[128 * 32];
    __shared__ unsigned short AlS[128 * 32];
    __shared__ unsigned short BhS[128 * 32];
    __shared__ unsigned short BlS[128 * 32];

    int tid = threadIdx.x, w = tid >> 6, lane = tid & 63;
    int m16 = lane & 15, qd = lane >> 4;
    int bn = blockIdx.x, bm = blockIdx.y;

    const unsigned short *Bh, *Bl;
    const float* bias;
    int mode;
    if (bn < 8)       { Bh = WqTh + (size_t)bn * 128 * D_;       Bl = WqTl + (size_t)bn * 128 * D_;       bias = bq + bn * 128;       mode = 0; }
    else if (bn < 16) { Bh = WkTh + (size_t)(bn - 8) * 128 * D_; Bl = WkTl + (size_t)(bn - 8) * 128 * D_; bias = bk + (bn - 8) * 128; mode = 1; }
    else              { Bh = WvTh; Bl = WvTl; bias = bvp; mode = 2; }

    int l4 = lane >> 2, c8 = (lane & 3) * 8;     // staging: row offset, k offset (elems)
    int rh = (w >> 1) * 64, chh = (w & 1) * 64;  // wave quadrant

    f32x4 acc[4][4];
#pragma unroll
    for (int it = 0; it < 4; it++)
#pragma unroll
        for (int jt = 0; jt < 4; jt++) acc[it][jt] = (f32x4){0.f, 0.f, 0.f, 0.f};

    int ra = tid >> 1, ca = (tid & 1) * 16;      // A staging: 16 floats/thread

    for (int k0 = 0; k0 < D_; k0 += 32) {
        // A: fp32 -> bf16 hi/lo (issue loads before barrier for overlap)
        const float* ax = x + (size_t)(bm * 128 + ra) * D_ + k0 + ca;
        float4 f0 = *(const float4*)(ax + 0);
        float4 f1 = *(const float4*)(ax + 4);
        float4 f2 = *(const float4*)(ax + 8);
        float4 f3 = *(const float4*)(ax + 12);
        __syncthreads();
        {
            float vv[16] = {f0.x, f0.y, f0.z, f0.w, f1.x, f1.y, f1.z, f1.w,
                            f2.x, f2.y, f2.z, f2.w, f3.x, f3.y, f3.z, f3.w};
            unsigned int hw[8], lw[8];
#pragma unroll
            for (int i = 0; i < 8; i++) {
                unsigned short h0 = f2bf(vv[2 * i]), h1 = f2bf(vv[2 * i + 1]);
                unsigned short l0 = f2bf(vv[2 * i] - bf2f(h0));
                unsigned short l1 = f2bf(vv[2 * i + 1] - bf2f(h1));
                hw[i] = (unsigned)h0 | ((unsigned)h1 << 16);
                lw[i] = (unsigned)l0 | ((unsigned)l1 << 16);
            }
            char* ah = (char*)AhS + ra * 64 + ca * 2;
            char* al = (char*)AlS + ra * 64 + ca * 2;
            *(uint4*)(ah + 0)  = make_uint4(hw[0], hw[1], hw[2], hw[3]);
            *(uint4*)(ah + 16) = make_uint4(hw[4], hw[5], hw[6], hw[7]);
            *(uint4*)(al + 0)  = make_uint4(lw[0], lw[1], lw[2], lw[3]);
            *(uint4*)(al + 16) = make_uint4(lw[4], lw[5], lw[6], lw[7]);
        }
        // B: async glds, wave w stages tile rows w*32..w*32+32
        {
            const unsigned short* gbh = Bh + (size_t)(w * 32 + l4) * D_ + k0 + c8;
            const unsigned short* gbl = Bl + (size_t)(w * 32 + l4) * D_ + k0 + c8;
            glds16(gbh,                     (char*)BhS + w * 2048);
            glds16(gbh + (size_t)16 * D_,   (char*)BhS + w * 2048 + 1024);
            glds16(gbl,                     (char*)BlS + w * 2048);
            glds16(gbl + (size_t)16 * D_,   (char*)BlS + w * 2048 + 1024);
        }
        __syncthreads();
        bf16x8 ah[4], al[4], bh[4], bl[4];
#pragma unroll
        for (int it = 0; it < 4; it++) {
            ah[it] = *(const bf16x8*)((char*)AhS + (rh + it * 16 + m16) * 64 + qd * 16);
            al[it] = *(const bf16x8*)((char*)AlS + (rh + it * 16 + m16) * 64 + qd * 16);
        }
#pragma unroll
        for (int jt = 0; jt < 4; jt++) {
            bh[jt] = *(const bf16x8*)((char*)BhS + (chh + jt * 16 + m16) * 64 + qd * 16);
            bl[jt] = *(const bf16x8*)((char*)BlS + (chh + jt * 16 + m16) * 64 + qd * 16);
        }
#pragma unroll
        for (int it = 0; it < 4; it++)
#pragma unroll
            for (int jt = 0; jt < 4; jt++) {
                acc[it][jt] = __builtin_amdgcn_mfma_f32_16x16x32_bf16(ah[it], bh[jt], acc[it][jt], 0, 0, 0);
                acc[it][jt] = __builtin_amdgcn_mfma_f32_16x16x32_bf16(ah[it], bl[jt], acc[it][jt], 0, 0, 0);
                acc[it][jt] = __builtin_amdgcn_mfma_f32_16x16x32_bf16(al[it], bh[jt], acc[it][jt], 0, 0, 0);
            }
    }
#pragma unroll
    for (int it = 0; it < 4; it++)
#pragma unroll
        for (int jt = 0; jt < 4; jt++)
#pragma unroll
            for (int r = 0; r < 4; r++) {
                int R = bm * 128 + rh + it * 16 + qd * 4 + r;
                int c = chh + jt * 16 + m16;
                float v = acc[it][jt][r] + bias[c];
                if (mode == 0) {
                    v *= 0.125f;
                    unsigned short h0 = f2bf(v);
                    qh[(size_t)R * D_ + bn * 128 + c] = h0;
                    ql[(size_t)R * D_ + bn * 128 + c] = f2bf(v - bf2f(h0));
                } else if (mode == 1) {
                    unsigned short h0 = f2bf(v);
                    kh[(size_t)R * D_ + (bn - 8) * 128 + c] = h0;
                    kl[(size_t)R * D_ + (bn - 8) * 128 + c] = f2bf(v - bf2f(h0));
                } else {
                    if (c < 64) vshb[(size_t)R * 64 + c] = v;
                }
            }
}

// ---------------- outg: x_out = och @ Wo + bo, 64x64 tile (4 blocks/CU), bf16 single, all glds ----------------
__global__ __launch_bounds__(256) void outg(const unsigned short* __restrict__ A,
                                            const unsigned short* __restrict__ Bh,
                                            const float* __restrict__ bias,
                                            float* __restrict__ C) {
    __shared__ unsigned short AhS[64 * 32];
    __shared__ unsigned short BhS[64 * 32];

    int tid = threadIdx.x, w = tid >> 6, lane = tid & 63;
    int m16 = lane & 15, qd = lane >> 4;
    int bn = blockIdx.x, bm = blockIdx.y;
    int l4 = lane >> 2, c8 = (lane & 3) * 8;
    int rh = (w >> 1) * 32, chh = (w & 1) * 32;

    f32x4 acc[2][2];
#pragma unroll
    for (int it = 0; it < 2; it++)
#pragma unroll
        for (int jt = 0; jt < 2; jt++) acc[it][jt] = (f32x4){0.f, 0.f, 0.f, 0.f};

    for (int k0 = 0; k0 < D_; k0 += 32) {
        __syncthreads();
        {
            const unsigned short* ga = A + (size_t)(bm * 64 + w * 16 + l4) * D_ + k0 + c8;
            glds16(ga, (char*)AhS + w * 1024);
            const unsigned short* gb = Bh + (size_t)(bn * 64 + w * 16 + l4) * D_ + k0 + c8;
            glds16(gb, (char*)BhS + w * 1024);
        }
        __syncthreads();
        bf16x8 ah[2], bh[2];
#pragma unroll
        for (int it = 0; it < 2; it++)
            ah[it] = *(const bf16x8*)((char*)AhS + (rh + it * 16 + m16) * 64 + qd * 16);
#pragma unroll
        for (int jt = 0; jt < 2; jt++)
            bh[jt] = *(const bf16x8*)((char*)BhS + (chh + jt * 16 + m16) * 64 + qd * 16);
#pragma unroll
        for (int it = 0; it < 2; it++)
#pragma unroll
            for (int jt = 0; jt < 2; jt++)
                acc[it][jt] = __builtin_amdgcn_mfma_f32_16x16x32_bf16(ah[it], bh[jt], acc[it][jt], 0, 0, 0);
    }
#pragma unroll
    for (int it = 0; it < 2; it++)
#pragma unroll
        for (int jt = 0; jt < 2; jt++)
#pragma unroll
            for (int r = 0; r < 4; r++) {
                int R = bm * 64 + rh + it * 16 + qd * 4 + r;
                int cc = bn * 64 + chh + jt * 16 + m16;
                C[(size_t)R * D_ + cc] = acc[it][jt][r] + bias[cc];
            }
}

// ---------------- fused attention v14: v12 (proven) + fused avg_attention atomics ----------------
// attn8 structure is v12 verbatim (143us, round-5 verified): 16 q-rows/block, 4 independent
// waves, ring-2 LDS K staging, qt-major decode, PV batch-gather, setprio on QK MFMA.
// New: the avg_attention reduction is fused into the tail. Slot values (already in regs
// as pA/wI for PV) are atomically accumulated into avg[row*S+key] * 1/16 directly
// (device-scope f32 atomics; rows disjoint per block, heads merge via atomics).
// sidx/sval/scnt global writes and the avg_reduce kernel are deleted; prep2 zeroes avg.
#define CCAP 48
__global__ __launch_bounds__(256, 4) void attn8(const unsigned short* __restrict__ qh,
                                                const unsigned short* __restrict__ ql,
                                                const unsigned short* __restrict__ kh,
                                                const unsigned short* __restrict__ kl,
                                                const float* __restrict__ vsh,
                                                unsigned short* __restrict__ och,
                                                float* __restrict__ avg) {
    // K staging: wave w owns KST + w*8192, two 4KB buffers (hi 2KB @ +0, lo 2KB @ +2048).
    __shared__ __align__(16) char KST[32768];
    __shared__ float smM[4][16];
    __shared__ float smS[4][16], smC[4][16];
    __shared__ float tau0s[16];
    __shared__ float taus[16];
    __shared__ int   ccnt[16];
    __shared__ int   ovfAny;
    __shared__ int   scnt16[16];

    // aliased into KST (first touched strictly after the post-QK barrier)
    float (*candV)[CCAP] = (float (*)[CCAP])(KST);          // 3072 B
    short (*candI)[CCAP] = (short (*)[CCAP])(KST + 3072);   // 1536 B
    float (*slotV)[16]   = (float (*)[16])(KST + 4608);     // 1024 B
    short (*slotI)[16]   = (short (*)[16])(KST + 5632);     //  512 B

    int tid = threadIdx.x, w = tid >> 6, lane = tid & 63;
    int m16 = lane & 15, qd = lane >> 4;

    // qt-major decode: same-XCD consecutive blocks share (bb,h), walk qt.
    int bid = blockIdx.x;
    int xcd = bid & 7;
    int j   = bid >> 3;                 // 0..511
    int bh  = ((j >> 6) << 3) | xcd;    // 0..63: fixed for 64 consecutive j on this XCD
    int qt  = j & 63;
    int bb  = bh >> 4, h = bh & 15;
    int row0g = bb * S_ + qt * 16;
    int kbase = bb * S_;

    // Q fragments (direct global, once)
    bf16x8 aH[2], aL[2];
#pragma unroll
    for (int c = 0; c < 2; c++) {
        size_t off = (size_t)(row0g + m16) * D_ + h * DH + c * 32 + qd * 8;
        aH[c] = *(const bf16x8*)(qh + off);
        aL[c] = *(const bf16x8*)(ql + off);
    }

    f32x4 Cfr[16];
#pragma unroll
    for (int t = 0; t < 16; t++) Cfr[t] = (f32x4){0.f, 0.f, 0.f, 0.f};

    // staging source: lane l covers row (l>>3), swizzled chunk (l&7)^(l>>3)
    char* myK = KST + w * 8192;
    {
        int sr = lane >> 3;
        int sc = (lane & 7) ^ sr;
        const unsigned short* ksh = kh + (size_t)(kbase + w * 256 + sr) * D_ + h * DH + sc * 8;
        const unsigned short* ksl = kl + (size_t)(kbase + w * 256 + sr) * D_ + h * DH + sc * 8;

#define STAGE_K(t, buf) do {                                        \
        size_t o_ = (size_t)(t) * 16 * D_;                          \
        char* db_ = myK + (buf) * 4096;                             \
        glds16(ksh + o_,                  db_);                     \
        glds16(ksh + o_ + (size_t)8 * D_, db_ + 1024);              \
        glds16(ksl + o_,                  db_ + 2048);              \
        glds16(ksl + o_ + (size_t)8 * D_, db_ + 3072);              \
    } while (0)

        // fragment read offsets (swizzled): chunk c*4+qd, row m16
        int sw0 = m16 * 128 + (((qd    ) ^ (m16 & 7)) << 4);
        int sw1 = m16 * 128 + (((4 + qd) ^ (m16 & 7)) << 4);

        STAGE_K(0, 0);
        asm volatile("s_waitcnt vmcnt(0)" ::: "memory");   // drains Q loads + tile 0
        __builtin_amdgcn_sched_barrier(0);

#pragma unroll
        for (int t = 0; t < 16; t++) {
            if (t < 15) {
                STAGE_K(t + 1, (t + 1) & 1);
                asm volatile("s_waitcnt vmcnt(4)" ::: "memory");   // tile t done, t+1 in flight
            } else {
                asm volatile("s_waitcnt vmcnt(0)" ::: "memory");
            }
            __builtin_amdgcn_sched_barrier(0);
            const char* tbuf = myK + (t & 1) * 4096;
            bf16x8 bfh0 = *(const bf16x8*)(tbuf + sw0);
            bf16x8 bfh1 = *(const bf16x8*)(tbuf + sw1);
            bf16x8 bfl0 = *(const bf16x8*)(tbuf + 2048 + sw0);
            bf16x8 bfl1 = *(const bf16x8*)(tbuf + 2048 + sw1);
            f32x4 a = Cfr[t];
            __builtin_amdgcn_s_setprio(1);
            a = __builtin_amdgcn_mfma_f32_16x16x32_bf16(aH[0], bfh0, a, 0, 0, 0);
            a = __builtin_amdgcn_mfma_f32_16x16x32_bf16(aH[1], bfh1, a, 0, 0, 0);
            a = __builtin_amdgcn_mfma_f32_16x16x32_bf16(aH[0], bfl0, a, 0, 0, 0);
            a = __builtin_amdgcn_mfma_f32_16x16x32_bf16(aH[1], bfl1, a, 0, 0, 0);
            a = __builtin_amdgcn_mfma_f32_16x16x32_bf16(aL[0], bfh0, a, 0, 0, 0);
            a = __builtin_amdgcn_mfma_f32_16x16x32_bf16(aL[1], bfh1, a, 0, 0, 0);
            __builtin_amdgcn_s_setprio(0);
            Cfr[t] = a;
        }
#undef STAGE_K
    }

    float mxr[4];
#pragma unroll
    for (int r = 0; r < 4; r++) mxr[r] = -3.0e38f;
#pragma unroll
    for (int t = 0; t < 16; t++)
#pragma unroll
        for (int r = 0; r < 4; r++) mxr[r] = fmaxf(mxr[r], Cfr[t][r]);
#pragma unroll
    for (int off = 8; off >= 1; off >>= 1)
#pragma unroll
        for (int r = 0; r < 4; r++) mxr[r] = fmaxf(mxr[r], __shfl_xor(mxr[r], off, 16));
    if (m16 == 0)
#pragma unroll
        for (int r = 0; r < 4; r++) smM[w][qd * 4 + r] = mxr[r];
    if (tid < 16) ccnt[tid] = 0;
    if (tid == 0) ovfAny = 0;
    __syncthreads();
    if (tid < 16)
        tau0s[tid] = fmaxf(fmaxf(smM[0][tid], smM[1][tid]), fmaxf(smM[2][tid], smM[3][tid])) - 1.0f;
    __syncthreads();

    float t0r[4];
#pragma unroll
    for (int r = 0; r < 4; r++) t0r[r] = tau0s[qd * 4 + r];

#pragma unroll
    for (int t = 0; t < 16; t++)
#pragma unroll
        for (int r = 0; r < 4; r++) {
            float z = Cfr[t][r];
            int row = qd * 4 + r;
            if (z > t0r[r]) {
                int pos = atomicAdd(&ccnt[row], 1);
                if (pos < CCAP) {
                    candV[row][pos] = z;
                    candI[row][pos] = (short)(w * 256 + t * 16 + m16);
                }
            }
        }
    __syncthreads();
    if (tid < 16 && ccnt[tid] > CCAP) ovfAny = 1;

    int prow = tid >> 4, pc = tid & 15;
    int nc = ccnt[prow];
    float tau = tau0s[prow];
    float z0 = -3.0e38f, z1 = -3.0e38f, z2 = -3.0e38f;
    if (nc <= CCAP) {
        z0 = (pc < nc)      ? candV[prow][pc]      : -3.0e38f;
        z1 = (pc + 16 < nc) ? candV[prow][pc + 16] : -3.0e38f;
        z2 = (pc + 32 < nc) ? candV[prow][pc + 32] : -3.0e38f;
        for (int it = 0; it < CCAP; it++) {
            float s = 0.f, c = 0.f;
            if (z0 > tau) { s += z0; c += 1.f; }
            if (z1 > tau) { s += z1; c += 1.f; }
            if (z2 > tau) { s += z2; c += 1.f; }
#pragma unroll
            for (int off = 8; off >= 1; off >>= 1) {
                s += __shfl_xor(s, off, 16);
                c += __shfl_xor(c, off, 16);
            }
            float tnew = (s - 1.f) / c;
            if (tnew > tau) tau = tnew; else break;
        }
    }
    if (pc == 0) taus[prow] = tau;
    if (tid < 16) scnt16[tid] = 0;
    __syncthreads();

    if (!ovfAny) {
        if (z0 > tau) {
            int sl = atomicAdd(&scnt16[prow], 1);
            if (sl < 16) { slotI[prow][sl] = candI[prow][pc]; slotV[prow][sl] = z0 - tau; }
        }
        if (z1 > tau) {
            int sl = atomicAdd(&scnt16[prow], 1);
            if (sl < 16) { slotI[prow][sl] = candI[prow][pc + 16]; slotV[prow][sl] = z1 - tau; }
        }
        if (z2 > tau) {
            int sl = atomicAdd(&scnt16[prow], 1);
            if (sl < 16) { slotI[prow][sl] = candI[prow][pc + 32]; slotV[prow][sl] = z2 - tau; }
        }
        __syncthreads();
    } else {
        for (int it = 0; it < 64; it++) {
            float s[4], c[4];
#pragma unroll
            for (int r = 0; r < 4; r++) { s[r] = 0.f; c[r] = 0.f; }
#pragma unroll
            for (int t = 0; t < 16; t++)
#pragma unroll
                for (int r = 0; r < 4; r++) {
                    float z = Cfr[t][r];
                    if (z > taus[qd * 4 + r]) { s[r] += z; c[r] += 1.f; }
                }
#pragma unroll
            for (int off = 8; off >= 1; off >>= 1)
#pragma unroll
                for (int r = 0; r < 4; r++) {
                    s[r] += __shfl_xor(s[r], off, 16);
                    c[r] += __shfl_xor(c[r], off, 16);
                }
            if (m16 == 0)
#pragma unroll
                for (int r = 0; r < 4; r++) {
                    smS[w][qd * 4 + r] = s[r];
                    smC[w][qd * 4 + r] = c[r];
                }
            __syncthreads();
            int done = 1;
            if (tid < 16) {
                float S = smS[0][tid] + smS[1][tid] + smS[2][tid] + smS[3][tid];
                float C = smC[0][tid] + smC[1][tid] + smC[2][tid] + smC[3][tid];
                float tnew = (S - 1.f) / C;
                if (C > 0.f && tnew > taus[tid]) { taus[tid] = tnew; done = 0; }
            }
            if (__syncthreads_and(done)) break;
        }
#pragma unroll
        for (int t = 0; t < 16; t++)
#pragma unroll
            for (int r = 0; r < 4; r++) {
                int row = qd * 4 + r;
                float p = Cfr[t][r] - taus[row];
                if (p > 0.f) {
                    int sl = atomicAdd(&scnt16[row], 1);
                    if (sl < 16) {
                        slotI[row][sl] = (short)(w * 256 + t * 16 + m16);
                        slotV[row][sl] = p;
                    }
                }
            }
        __syncthreads();
    }

    int nsl = min(scnt16[prow], 16);
    // ---- PV batch-gather: wide LDS reads, then all 16 V-loads independent ----
    f32x4 v0 = *(const f32x4*)&slotV[prow][0];
    f32x4 v1 = *(const f32x4*)&slotV[prow][4];
    f32x4 v2 = *(const f32x4*)&slotV[prow][8];
    f32x4 v3 = *(const f32x4*)&slotV[prow][12];
    const uint4* sIv = (const uint4*)&slotI[prow][0];
    uint4 i0 = sIv[0], i1 = sIv[1];
    float pA[16] = {v0[0], v0[1], v0[2], v0[3], v1[0], v1[1], v1[2], v1[3],
                    v2[0], v2[1], v2[2], v2[3], v3[0], v3[1], v3[2], v3[3]};
    unsigned wI[8] = {i0.x, i0.y, i0.z, i0.w, i1.x, i1.y, i1.z, i1.w};
    float4 accq = make_float4(0.f, 0.f, 0.f, 0.f);
#pragma unroll
    for (int sl = 0; sl < 16; sl++) {
        float p = (sl < nsl) ? pA[sl] : 0.f;
        int key = (int)((wI[sl >> 1] >> ((sl & 1) * 16)) & 1023u);
        float4 vv = *(const float4*)(vsh + (size_t)(kbase + key) * DH + pc * 4);
        accq.x += p * vv.x;
        accq.y += p * vv.y;
        accq.z += p * vv.z;
        accq.w += p * vv.w;
    }
    {
        unsigned short b0 = f2bf(accq.x), b1 = f2bf(accq.y), b2 = f2bf(accq.z), b3 = f2bf(accq.w);
        *(uint2*)(och + (size_t)(row0g + prow) * D_ + h * DH + pc * 4) =
            make_uint2((unsigned)b0 | ((unsigned)b1 << 16), (unsigned)b2 | ((unsigned)b3 << 16));
    }
    // ---- fused avg_attention: thread (prow, pc) accumulates slot pc of its row ----
    if (pc < nsl) {
        int key = (int)((wI[pc >> 1] >> ((pc & 1) * 16)) & 1023u);
        atomicAdd(avg + (size_t)(row0g + prow) * S_ + key, pA[pc] * 0.0625f);
    }
}

extern "C" void kernel_launch(void* const* d_in, const int* in_sizes, int n_in,
                              void* d_out, int out_size, void* d_ws, size_t ws_size,
                              hipStream_t stream) {
    const float* x  = (const float*)d_in[0];
    const float* Wq = (const float*)d_in[1];
    const float* bq = (const float*)d_in[2];
    const float* Wk = (const float*)d_in[3];
    const float* bk = (const float*)d_in[4];
    const float* Wv = (const float*)d_in[5];
    const float* bv = (const float*)d_in[6];
    const float* Wo = (const float*)d_in[7];
    const float* bo = (const float*)d_in[8];

    float* xout = (float*)d_out;                   // (B,S,D)
    float* avg  = xout + (size_t)BS * D_;          // (B,S,S)

    char* ws = (char*)d_ws;
    unsigned short* qhB  = (unsigned short*)(ws + 0);               // 8 MB
    unsigned short* qlB  = (unsigned short*)(ws + (8u << 20));      // 8 MB
    unsigned short* khB  = (unsigned short*)(ws + (16u << 20));     // 8 MB
    unsigned short* klB  = (unsigned short*)(ws + (24u << 20));     // 8 MB
    unsigned short* WqTh = (unsigned short*)(ws + (32u << 20));     // 2 MB
    unsigned short* WqTl = (unsigned short*)(ws + (34u << 20));     // 2 MB
    unsigned short* WkTh = (unsigned short*)(ws + (36u << 20));     // 2 MB
    unsigned short* WkTl = (unsigned short*)(ws + (38u << 20));     // 2 MB
    unsigned short* ochB = WqTh;                                    // alias 32..40 MB (dead after projg)
    unsigned short* WoTh = (unsigned short*)(ws + (40u << 20));     // 2 MB
    unsigned short* WvTh = (unsigned short*)(ws + (42u << 20));     // 256 KB (128x1024 bf16)
    unsigned short* WvTl = (unsigned short*)(ws + (42u << 20) + (256u << 10));  // 256 KB
    float* bvp = (float*)(ws + (42u << 20) + (512u << 10));         // 512 B
    float* vshb = (float*)(ws + (43u << 20));                       // 1 MB

    prep2<<<7680, 256, 0, stream>>>(Wq, Wk, Wo, Wv, bv, WqTh, WqTl, WkTh, WkTl, WoTh, WvTh, WvTl, bvp, avg);
    projg<<<dim3(17, 32), 256, 0, stream>>>(x, WqTh, WqTl, WkTh, WkTl, WvTh, WvTl,
                                            bq, bk, bvp, qhB, qlB, khB, klB, vshb);
    attn8<<<4096, 256, 0, stream>>>(qhB, qlB, khB, klB, vshb, ochB, avg);
    outg<<<dim3(16, 64), 256, 0, stream>>>(ochB, WoTh, bo, xout);
}

// Round 8
// 338.870 us; speedup vs baseline: 2.6337x; 1.0287x over previous
//
#include <hip/hip_runtime.h>

#define B_  4
#define S_  1024
#define D_  1024
#define H_  16
#define DH  64
#define BS  4096   // B_*S_

typedef __bf16 bf16x8 __attribute__((ext_vector_type(8)));
typedef float  f32x4  __attribute__((ext_vector_type(4)));

__device__ __forceinline__ unsigned short f2bf(float f) {
    __bf16 b = (__bf16)f;
    return __builtin_bit_cast(unsigned short, b);
}
__device__ __forceinline__ float bf2f(unsigned short u) {
    return (float)__builtin_bit_cast(__bf16, u);
}
// async global->LDS, 16B/lane; LDS dest = wave-uniform base + lane*16
__device__ __forceinline__ void glds16(const void* g, void* l) {
    __builtin_amdgcn_global_load_lds((const __attribute__((address_space(1))) void*)g,
                                     (__attribute__((address_space(3))) void*)l, 16, 0, 0);
}

// ---------------- prep2: weight transp+hi/lo, Wvsh^T, bvp, avg zero, (opt) x->bf16 hilo ----------------
// grid 7680 (small-ws) or 9728 (big-ws): bid<3072 transpose, 3072..3327 Wvsh^T,
// 3328..3583 pad, 3584..7679 zero avg, 7680..9727 x conversion (big-ws only).
__global__ __launch_bounds__(256) void prep2(const float* __restrict__ Wq,
                                             const float* __restrict__ Wk,
                                             const float* __restrict__ Wo,
                                             const float* __restrict__ Wv,
                                             const float* __restrict__ bv,
                                             const float* __restrict__ x,
                                             unsigned short* __restrict__ WqTh,
                                             unsigned short* __restrict__ WqTl,
                                             unsigned short* __restrict__ WkTh,
                                             unsigned short* __restrict__ WkTl,
                                             unsigned short* __restrict__ WoTh,
                                             unsigned short* __restrict__ WvTh,
                                             unsigned short* __restrict__ WvTl,
                                             float* __restrict__ bvp,
                                             float* __restrict__ avg,
                                             unsigned short* __restrict__ xh,
                                             unsigned short* __restrict__ xl) {
    __shared__ float tile[32][33];
    int bid = blockIdx.x, tid = threadIdx.x;
    if (bid < 3072) {
        const float* W;
        unsigned short *Th, *Tl;
        int wantLo;
        if (bid < 1024)      { W = Wq; Th = WqTh; Tl = WqTl; wantLo = 1; }
        else if (bid < 2048) { W = Wk; Th = WkTh; Tl = WkTl; wantLo = 1; bid -= 1024; }
        else                 { W = Wo; Th = WoTh; Tl = nullptr; wantLo = 0; bid -= 2048; }
        int tn = bid & 31, tk = bid >> 5;
        int r = tid >> 3, c4 = (tid & 7) * 4;
        float4 v = *(const float4*)(W + (size_t)(tk * 32 + r) * D_ + tn * 32 + c4);
        tile[r][c4 + 0] = v.x;
        tile[r][c4 + 1] = v.y;
        tile[r][c4 + 2] = v.z;
        tile[r][c4 + 3] = v.w;
        __syncthreads();
        unsigned short hh[4], ll[4];
#pragma unroll
        for (int i = 0; i < 4; i++) {
            float f = tile[c4 + i][r];
            hh[i] = f2bf(f);
            ll[i] = f2bf(f - bf2f(hh[i]));
        }
        size_t off = (size_t)(tn * 32 + r) * D_ + tk * 32 + c4;
        *(uint2*)(Th + off) = make_uint2((unsigned)hh[0] | ((unsigned)hh[1] << 16),
                                         (unsigned)hh[2] | ((unsigned)hh[3] << 16));
        if (wantLo)
            *(uint2*)(Tl + off) = make_uint2((unsigned)ll[0] | ((unsigned)ll[1] << 16),
                                             (unsigned)ll[2] | ((unsigned)ll[3] << 16));
    } else if (bid < 3328) {
        // Wvsh^T rows 0..63: WvT[j][d] = mean_h Wv[d][h*64+j], hi/lo
        int e = (bid - 3072) * 256 + tid;      // 0..65535
        int d = e >> 6, j = e & 63;
        float s = 0.f;
#pragma unroll
        for (int hh = 0; hh < H_; hh++) s += Wv[(size_t)d * D_ + hh * DH + j];
        s *= (1.f / 16.f);
        unsigned short hi = f2bf(s);
        WvTh[(size_t)j * D_ + d] = hi;
        WvTl[(size_t)j * D_ + d] = f2bf(s - bf2f(hi));
        if (bid == 3072 && tid < 128) {
            float sb = 0.f;
            if (tid < 64) {
#pragma unroll
                for (int hh = 0; hh < H_; hh++) sb += bv[hh * DH + tid];
                sb *= (1.f / 16.f);
            }
            bvp[tid] = sb;
        }
    } else if (bid < 3584) {
        // zero-pad rows 64..127 of Wvsh^T
        int e = (bid - 3328) * 256 + tid;      // 0..65535
        int row = 64 + (e >> 10), col = e & 1023;
        WvTh[(size_t)row * D_ + col] = 0;
        WvTl[(size_t)row * D_ + col] = 0;
    } else if (bid < 7680) {
        // zero avg (B,S,S) = 4M floats: 4096 blocks x 256 threads x float4
        int e = (bid - 3584) * 256 + tid;      // 0..1048575
        *(float4*)(avg + (size_t)e * 4) = make_float4(0.f, 0.f, 0.f, 0.f);
    } else {
        // x -> bf16 hi/lo, 8 elems/thread: 2048 blocks x 256 threads x 8 = 4M elems
        size_t base = ((size_t)(bid - 7680) * 256 + tid) * 8;
        float4 f0 = *(const float4*)(x + base);
        float4 f1 = *(const float4*)(x + base + 4);
        float vv[8] = {f0.x, f0.y, f0.z, f0.w, f1.x, f1.y, f1.z, f1.w};
        unsigned hw[4], lw[4];
#pragma unroll
        for (int i = 0; i < 4; i++) {
            unsigned short h0 = f2bf(vv[2 * i]), h1 = f2bf(vv[2 * i + 1]);
            unsigned short l0 = f2bf(vv[2 * i] - bf2f(h0));
            unsigned short l1 = f2bf(vv[2 * i + 1] - bf2f(h1));
            hw[i] = (unsigned)h0 | ((unsigned)h1 << 16);
            lw[i] = (unsigned)l0 | ((unsigned)l1 << 16);
        }
        *(uint4*)(xh + base) = make_uint4(hw[0], hw[1], hw[2], hw[3]);
        *(uint4*)(xl + base) = make_uint4(lw[0], lw[1], lw[2], lw[3]);
    }
}

// ---------------- projg (legacy, small-ws fallback): inline x conversion ----------------
__global__ __launch_bounds__(256) void projg(const float* __restrict__ x,
                                             const unsigned short* __restrict__ WqTh, const unsigned short* __restrict__ WqTl,
                                             const unsigned short* __restrict__ WkTh, const unsigned short* __restrict__ WkTl,
                                             const unsigned short* __restrict__ WvTh, const unsigned short* __restrict__ WvTl,
                                             const float* __restrict__ bq, const float* __restrict__ bk,
                                             const float* __restrict__ bvp,
                                             unsigned short* __restrict__ qh, unsigned short* __restrict__ ql,
                                             unsigned short* __restrict__ kh, unsigned short* __restrict__ kl,
                                             float* __restrict__ vshb) {
    __shared__ unsigned short AhS[128 * 32];
    __shared__ unsigned short AlS[128 * 32];
    __shared__ unsigned short BhS[128 * 32];
    __shared__ unsigned short BlS[128 * 32];

    int tid = threadIdx.x, w = tid >> 6, lane = tid & 63;
    int m16 = lane & 15, qd = lane >> 4;
    int bn = blockIdx.x, bm = blockIdx.y;

    const unsigned short *Bh, *Bl;
    const float* bias;
    int mode;
    if (bn < 8)       { Bh = WqTh + (size_t)bn * 128 * D_;       Bl = WqTl + (size_t)bn * 128 * D_;       bias = bq + bn * 128;       mode = 0; }
    else if (bn < 16) { Bh = WkTh + (size_t)(bn - 8) * 128 * D_; Bl = WkTl + (size_t)(bn - 8) * 128 * D_; bias = bk + (bn - 8) * 128; mode = 1; }
    else              { Bh = WvTh; Bl = WvTl; bias = bvp; mode = 2; }

    int l4 = lane >> 2, c8 = (lane & 3) * 8;
    int rh = (w >> 1) * 64, chh = (w & 1) * 64;

    f32x4 acc[4][4];
#pragma unroll
    for (int it = 0; it < 4; it++)
#pragma unroll
        for (int jt = 0; jt < 4; jt++) acc[it][jt] = (f32x4){0.f, 0.f, 0.f, 0.f};

    int ra = tid >> 1, ca = (tid & 1) * 16;

    for (int k0 = 0; k0 < D_; k0 += 32) {
        const float* ax = x + (size_t)(bm * 128 + ra) * D_ + k0 + ca;
        float4 f0 = *(const float4*)(ax + 0);
        float4 f1 = *(const float4*)(ax + 4);
        float4 f2 = *(const float4*)(ax + 8);
        float4 f3 = *(const float4*)(ax + 12);
        __syncthreads();
        {
            float vv[16] = {f0.x, f0.y, f0.z, f0.w, f1.x, f1.y, f1.z, f1.w,
                            f2.x, f2.y, f2.z, f2.w, f3.x, f3.y, f3.z, f3.w};
            unsigned int hw[8], lw[8];
#pragma unroll
            for (int i = 0; i < 8; i++) {
                unsigned short h0 = f2bf(vv[2 * i]), h1 = f2bf(vv[2 * i + 1]);
                unsigned short l0 = f2bf(vv[2 * i] - bf2f(h0));
                unsigned short l1 = f2bf(vv[2 * i + 1] - bf2f(h1));
                hw[i] = (unsigned)h0 | ((unsigned)h1 << 16);
                lw[i] = (unsigned)l0 | ((unsigned)l1 << 16);
            }
            char* ah = (char*)AhS + ra * 64 + ca * 2;
            char* al = (char*)AlS + ra * 64 + ca * 2;
            *(uint4*)(ah + 0)  = make_uint4(hw[0], hw[1], hw[2], hw[3]);
            *(uint4*)(ah + 16) = make_uint4(hw[4], hw[5], hw[6], hw[7]);
            *(uint4*)(al + 0)  = make_uint4(lw[0], lw[1], lw[2], lw[3]);
            *(uint4*)(al + 16) = make_uint4(lw[4], lw[5], lw[6], lw[7]);
        }
        {
            const unsigned short* gbh = Bh + (size_t)(w * 32 + l4) * D_ + k0 + c8;
            const unsigned short* gbl = Bl + (size_t)(w * 32 + l4) * D_ + k0 + c8;
            glds16(gbh,                     (char*)BhS + w * 2048);
            glds16(gbh + (size_t)16 * D_,   (char*)BhS + w * 2048 + 1024);
            glds16(gbl,                     (char*)BlS + w * 2048);
            glds16(gbl + (size_t)16 * D_,   (char*)BlS + w * 2048 + 1024);
        }
        __syncthreads();
        bf16x8 ah[4], al[4], bh[4], bl[4];
#pragma unroll
        for (int it = 0; it < 4; it++) {
            ah[it] = *(const bf16x8*)((char*)AhS + (rh + it * 16 + m16) * 64 + qd * 16);
            al[it] = *(const bf16x8*)((char*)AlS + (rh + it * 16 + m16) * 64 + qd * 16);
        }
#pragma unroll
        for (int jt = 0; jt < 4; jt++) {
            bh[jt] = *(const bf16x8*)((char*)BhS + (chh + jt * 16 + m16) * 64 + qd * 16);
            bl[jt] = *(const bf16x8*)((char*)BlS + (chh + jt * 16 + m16) * 64 + qd * 16);
        }
#pragma unroll
        for (int it = 0; it < 4; it++)
#pragma unroll
            for (int jt = 0; jt < 4; jt++) {
                acc[it][jt] = __builtin_amdgcn_mfma_f32_16x16x32_bf16(ah[it], bh[jt], acc[it][jt], 0, 0, 0);
                acc[it][jt] = __builtin_amdgcn_mfma_f32_16x16x32_bf16(ah[it], bl[jt], acc[it][jt], 0, 0, 0);
                acc[it][jt] = __builtin_amdgcn_mfma_f32_16x16x32_bf16(al[it], bh[jt], acc[it][jt], 0, 0, 0);
            }
    }
#pragma unroll
    for (int it = 0; it < 4; it++)
#pragma unroll
        for (int jt = 0; jt < 4; jt++)
#pragma unroll
            for (int r = 0; r < 4; r++) {
                int R = bm * 128 + rh + it * 16 + qd * 4 + r;
                int c = chh + jt * 16 + m16;
                float v = acc[it][jt][r] + bias[c];
                if (mode == 0) {
                    v *= 0.125f;
                    unsigned short h0 = f2bf(v);
                    qh[(size_t)R * D_ + bn * 128 + c] = h0;
                    ql[(size_t)R * D_ + bn * 128 + c] = f2bf(v - bf2f(h0));
                } else if (mode == 1) {
                    unsigned short h0 = f2bf(v);
                    kh[(size_t)R * D_ + (bn - 8) * 128 + c] = h0;
                    kl[(size_t)R * D_ + (bn - 8) * 128 + c] = f2bf(v - bf2f(h0));
                } else {
                    if (c < 64) vshb[(size_t)R * 64 + c] = v;
                }
            }
}

// ---------------- projgx (big-ws): A from precomputed xh/xl via glds16 (outg pattern) ----------------
// Removes the 17x-redundant per-block fp32->bf16 conversion (was ~3-4K VALU instr/thread).
// k-step = barrier -> 8 glds16 (A hi/lo + B hi/lo) -> barrier -> ds_read + 48 MFMA.
__global__ __launch_bounds__(256) void projgx(const unsigned short* __restrict__ xh,
                                              const unsigned short* __restrict__ xl,
                                              const unsigned short* __restrict__ WqTh, const unsigned short* __restrict__ WqTl,
                                              const unsigned short* __restrict__ WkTh, const unsigned short* __restrict__ WkTl,
                                              const unsigned short* __restrict__ WvTh, const unsigned short* __restrict__ WvTl,
                                              const float* __restrict__ bq, const float* __restrict__ bk,
                                              const float* __restrict__ bvp,
                                              unsigned short* __restrict__ qh, unsigned short* __restrict__ ql,
                                              unsigned short* __restrict__ kh, unsigned short* __restrict__ kl,
                                              float* __restrict__ vshb) {
    __shared__ unsigned short AhS[128 * 32];
    __shared__ unsigned short AlS[128 * 32];
    __shared__ unsigned short BhS[128 * 32];
    __shared__ unsigned short BlS[128 * 32];

    int tid = threadIdx.x, w = tid >> 6, lane = tid & 63;
    int m16 = lane & 15, qd = lane >> 4;
    int bn = blockIdx.x, bm = blockIdx.y;

    const unsigned short *Bh, *Bl;
    const float* bias;
    int mode;
    if (bn < 8)       { Bh = WqTh + (size_t)bn * 128 * D_;       Bl = WqTl + (size_t)bn * 128 * D_;       bias = bq + bn * 128;       mode = 0; }
    else if (bn < 16) { Bh = WkTh + (size_t)(bn - 8) * 128 * D_; Bl = WkTl + (size_t)(bn - 8) * 128 * D_; bias = bk + (bn - 8) * 128; mode = 1; }
    else              { Bh = WvTh; Bl = WvTl; bias = bvp; mode = 2; }

    int l4 = lane >> 2, c8 = (lane & 3) * 8;
    int rh = (w >> 1) * 64, chh = (w & 1) * 64;

    f32x4 acc[4][4];
#pragma unroll
    for (int it = 0; it < 4; it++)
#pragma unroll
        for (int jt = 0; jt < 4; jt++) acc[it][jt] = (f32x4){0.f, 0.f, 0.f, 0.f};

    for (int k0 = 0; k0 < D_; k0 += 32) {
        __syncthreads();   // prior iteration's LDS reads complete before overwrite
        {
            const unsigned short* gah = xh + (size_t)(bm * 128 + w * 32 + l4) * D_ + k0 + c8;
            const unsigned short* gal = xl + (size_t)(bm * 128 + w * 32 + l4) * D_ + k0 + c8;
            glds16(gah,                     (char*)AhS + w * 2048);
            glds16(gah + (size_t)16 * D_,   (char*)AhS + w * 2048 + 1024);
            glds16(gal,                     (char*)AlS + w * 2048);
            glds16(gal + (size_t)16 * D_,   (char*)AlS + w * 2048 + 1024);
            const unsigned short* gbh = Bh + (size_t)(w * 32 + l4) * D_ + k0 + c8;
            const unsigned short* gbl = Bl + (size_t)(w * 32 + l4) * D_ + k0 + c8;
            glds16(gbh,                     (char*)BhS + w * 2048);
            glds16(gbh + (size_t)16 * D_,   (char*)BhS + w * 2048 + 1024);
            glds16(gbl,                     (char*)BlS + w * 2048);
            glds16(gbl + (size_t)16 * D_,   (char*)BlS + w * 2048 + 1024);
        }
        __syncthreads();   // barrier drains vmcnt (compiler-inserted) -> staged data visible
        bf16x8 ah[4], al[4], bh[4], bl[4];
#pragma unroll
        for (int it = 0; it < 4; it++) {
            ah[it] = *(const bf16x8*)((char*)AhS + (rh + it * 16 + m16) * 64 + qd * 16);
            al[it] = *(const bf16x8*)((char*)AlS + (rh + it * 16 + m16) * 64 + qd * 16);
        }
#pragma unroll
        for (int jt = 0; jt < 4; jt++) {
            bh[jt] = *(const bf16x8*)((char*)BhS + (chh + jt * 16 + m16) * 64 + qd * 16);
            bl[jt] = *(const bf16x8*)((char*)BlS + (chh + jt * 16 + m16) * 64 + qd * 16);
        }
#pragma unroll
        for (int it = 0; it < 4; it++)
#pragma unroll
            for (int jt = 0; jt < 4; jt++) {
                acc[it][jt] = __builtin_amdgcn_mfma_f32_16x16x32_bf16(ah[it], bh[jt], acc[it][jt], 0, 0, 0);
                acc[it][jt] = __builtin_amdgcn_mfma_f32_16x16x32_bf16(ah[it], bl[jt], acc[it][jt], 0, 0, 0);
                acc[it][jt] = __builtin_amdgcn_mfma_f32_16x16x32_bf16(al[it], bh[jt], acc[it][jt], 0, 0, 0);
            }
    }
#pragma unroll
    for (int it = 0; it < 4; it++)
#pragma unroll
        for (int jt = 0; jt < 4; jt++)
#pragma unroll
            for (int r = 0; r < 4; r++) {
                int R = bm * 128 + rh + it * 16 + qd * 4 + r;
                int c = chh + jt * 16 + m16;
                float v = acc[it][jt][r] + bias[c];
                if (mode == 0) {
                    v *= 0.125f;
                    unsigned short h0 = f2bf(v);
                    qh[(size_t)R * D_ + bn * 128 + c] = h0;
                    ql[(size_t)R * D_ + bn * 128 + c] = f2bf(v - bf2f(h0));
                } else if (mode == 1) {
                    unsigned short h0 = f2bf(v);
                    kh[(size_t)R * D_ + (bn - 8) * 128 + c] = h0;
                    kl[(size_t)R * D_ + (bn - 8) * 128 + c] = f2bf(v - bf2f(h0));
                } else {
                    if (c < 64) vshb[(size_t)R * 64 + c] = v;
                }
            }
}

// ---------------- outg: x_out = och @ Wo + bo, 64x64 tile (4 blocks/CU), bf16 single, all glds ----------------
__global__ __launch_bounds__(256) void outg(const unsigned short* __restrict__ A,
                                            const unsigned short* __restrict__ Bh,
                                            const float* __restrict__ bias,
                                            float* __restrict__ C) {
    __shared__ unsigned short AhS[64 * 32];
    __shared__ unsigned short BhS[64 * 32];

    int tid = threadIdx.x, w = tid >> 6, lane = tid & 63;
    int m16 = lane & 15, qd = lane >> 4;
    int bn = blockIdx.x, bm = blockIdx.y;
    int l4 = lane >> 2, c8 = (lane & 3) * 8;
    int rh = (w >> 1) * 32, chh = (w & 1) * 32;

    f32x4 acc[2][2];
#pragma unroll
    for (int it = 0; it < 2; it++)
#pragma unroll
        for (int jt = 0; jt < 2; jt++) acc[it][jt] = (f32x4){0.f, 0.f, 0.f, 0.f};

    for (int k0 = 0; k0 < D_; k0 += 32) {
        __syncthreads();
        {
            const unsigned short* ga = A + (size_t)(bm * 64 + w * 16 + l4) * D_ + k0 + c8;
            glds16(ga, (char*)AhS + w * 1024);
            const unsigned short* gb = Bh + (size_t)(bn * 64 + w * 16 + l4) * D_ + k0 + c8;
            glds16(gb, (char*)BhS + w * 1024);
        }
        __syncthreads();
        bf16x8 ah[2], bh[2];
#pragma unroll
        for (int it = 0; it < 2; it++)
            ah[it] = *(const bf16x8*)((char*)AhS + (rh + it * 16 + m16) * 64 + qd * 16);
#pragma unroll
        for (int jt = 0; jt < 2; jt++)
            bh[jt] = *(const bf16x8*)((char*)BhS + (chh + jt * 16 + m16) * 64 + qd * 16);
#pragma unroll
        for (int it = 0; it < 2; it++)
#pragma unroll
            for (int jt = 0; jt < 2; jt++)
                acc[it][jt] = __builtin_amdgcn_mfma_f32_16x16x32_bf16(ah[it], bh[jt], acc[it][jt], 0, 0, 0);
    }
#pragma unroll
    for (int it = 0; it < 2; it++)
#pragma unroll
        for (int jt = 0; jt < 2; jt++)
#pragma unroll
            for (int r = 0; r < 4; r++) {
                int R = bm * 64 + rh + it * 16 + qd * 4 + r;
                int cc = bn * 64 + chh + jt * 16 + m16;
                C[(size_t)R * D_ + cc] = acc[it][jt][r] + bias[cc];
            }
}

// ---------------- fused attention v14 (round-7 verified, verbatim) ----------------
#define CCAP 48
__global__ __launch_bounds__(256, 4) void attn8(const unsigned short* __restrict__ qh,
                                                const unsigned short* __restrict__ ql,
                                                const unsigned short* __restrict__ kh,
                                                const unsigned short* __restrict__ kl,
                                                const float* __restrict__ vsh,
                                                unsigned short* __restrict__ och,
                                                float* __restrict__ avg) {
    // K staging: wave w owns KST + w*8192, two 4KB buffers (hi 2KB @ +0, lo 2KB @ +2048).
    __shared__ __align__(16) char KST[32768];
    __shared__ float smM[4][16];
    __shared__ float smS[4][16], smC[4][16];
    __shared__ float tau0s[16];
    __shared__ float taus[16];
    __shared__ int   ccnt[16];
    __shared__ int   ovfAny;
    __shared__ int   scnt16[16];

    // aliased into KST (first touched strictly after the post-QK barrier)
    float (*candV)[CCAP] = (float (*)[CCAP])(KST);          // 3072 B
    short (*candI)[CCAP] = (short (*)[CCAP])(KST + 3072);   // 1536 B
    float (*slotV)[16]   = (float (*)[16])(KST + 4608);     // 1024 B
    short (*slotI)[16]   = (short (*)[16])(KST + 5632);     //  512 B

    int tid = threadIdx.x, w = tid >> 6, lane = tid & 63;
    int m16 = lane & 15, qd = lane >> 4;

    // qt-major decode: same-XCD consecutive blocks share (bb,h), walk qt.
    int bid = blockIdx.x;
    int xcd = bid & 7;
    int j   = bid >> 3;                 // 0..511
    int bh  = ((j >> 6) << 3) | xcd;    // 0..63
    int qt  = j & 63;
    int bb  = bh >> 4, h = bh & 15;
    int row0g = bb * S_ + qt * 16;
    int kbase = bb * S_;

    // Q fragments (direct global, once)
    bf16x8 aH[2], aL[2];
#pragma unroll
    for (int c = 0; c < 2; c++) {
        size_t off = (size_t)(row0g + m16) * D_ + h * DH + c * 32 + qd * 8;
        aH[c] = *(const bf16x8*)(qh + off);
        aL[c] = *(const bf16x8*)(ql + off);
    }

    f32x4 Cfr[16];
#pragma unroll
    for (int t = 0; t < 16; t++) Cfr[t] = (f32x4){0.f, 0.f, 0.f, 0.f};

    // staging source: lane l covers row (l>>3), swizzled chunk (l&7)^(l>>3)
    char* myK = KST + w * 8192;
    {
        int sr = lane >> 3;
        int sc = (lane & 7) ^ sr;
        const unsigned short* ksh = kh + (size_t)(kbase + w * 256 + sr) * D_ + h * DH + sc * 8;
        const unsigned short* ksl = kl + (size_t)(kbase + w * 256 + sr) * D_ + h * DH + sc * 8;

#define STAGE_K(t, buf) do {                                        \
        size_t o_ = (size_t)(t) * 16 * D_;                          \
        char* db_ = myK + (buf) * 4096;                             \
        glds16(ksh + o_,                  db_);                     \
        glds16(ksh + o_ + (size_t)8 * D_, db_ + 1024);              \
        glds16(ksl + o_,                  db_ + 2048);              \
        glds16(ksl + o_ + (size_t)8 * D_, db_ + 3072);              \
    } while (0)

        // fragment read offsets (swizzled): chunk c*4+qd, row m16
        int sw0 = m16 * 128 + (((qd    ) ^ (m16 & 7)) << 4);
        int sw1 = m16 * 128 + (((4 + qd) ^ (m16 & 7)) << 4);

        STAGE_K(0, 0);
        asm volatile("s_waitcnt vmcnt(0)" ::: "memory");   // drains Q loads + tile 0
        __builtin_amdgcn_sched_barrier(0);

#pragma unroll
        for (int t = 0; t < 16; t++) {
            if (t < 15) {
                STAGE_K(t + 1, (t + 1) & 1);
                asm volatile("s_waitcnt vmcnt(4)" ::: "memory");   // tile t done, t+1 in flight
            } else {
                asm volatile("s_waitcnt vmcnt(0)" ::: "memory");
            }
            __builtin_amdgcn_sched_barrier(0);
            const char* tbuf = myK + (t & 1) * 4096;
            bf16x8 bfh0 = *(const bf16x8*)(tbuf + sw0);
            bf16x8 bfh1 = *(const bf16x8*)(tbuf + sw1);
            bf16x8 bfl0 = *(const bf16x8*)(tbuf + 2048 + sw0);
            bf16x8 bfl1 = *(const bf16x8*)(tbuf + 2048 + sw1);
            f32x4 a = Cfr[t];
            __builtin_amdgcn_s_setprio(1);
            a = __builtin_amdgcn_mfma_f32_16x16x32_bf16(aH[0], bfh0, a, 0, 0, 0);
            a = __builtin_amdgcn_mfma_f32_16x16x32_bf16(aH[1], bfh1, a, 0, 0, 0);
            a = __builtin_amdgcn_mfma_f32_16x16x32_bf16(aH[0], bfl0, a, 0, 0, 0);
            a = __builtin_amdgcn_mfma_f32_16x16x32_bf16(aH[1], bfl1, a, 0, 0, 0);
            a = __builtin_amdgcn_mfma_f32_16x16x32_bf16(aL[0], bfh0, a, 0, 0, 0);
            a = __builtin_amdgcn_mfma_f32_16x16x32_bf16(aL[1], bfh1, a, 0, 0, 0);
            __builtin_amdgcn_s_setprio(0);
            Cfr[t] = a;
        }
#undef STAGE_K
    }

    float mxr[4];
#pragma unroll
    for (int r = 0; r < 4; r++) mxr[r] = -3.0e38f;
#pragma unroll
    for (int t = 0; t < 16; t++)
#pragma unroll
        for (int r = 0; r < 4; r++) mxr[r] = fmaxf(mxr[r], Cfr[t][r]);
#pragma unroll
    for (int off = 8; off >= 1; off >>= 1)
#pragma unroll
        for (int r = 0; r < 4; r++) mxr[r] = fmaxf(mxr[r], __shfl_xor(mxr[r], off, 16));
    if (m16 == 0)
#pragma unroll
        for (int r = 0; r < 4; r++) smM[w][qd * 4 + r] = mxr[r];
    if (tid < 16) ccnt[tid] = 0;
    if (tid == 0) ovfAny = 0;
    __syncthreads();
    if (tid < 16)
        tau0s[tid] = fmaxf(fmaxf(smM[0][tid], smM[1][tid]), fmaxf(smM[2][tid], smM[3][tid])) - 1.0f;
    __syncthreads();

    float t0r[4];
#pragma unroll
    for (int r = 0; r < 4; r++) t0r[r] = tau0s[qd * 4 + r];

#pragma unroll
    for (int t = 0; t < 16; t++)
#pragma unroll
        for (int r = 0; r < 4; r++) {
            float z = Cfr[t][r];
            int row = qd * 4 + r;
            if (z > t0r[r]) {
                int pos = atomicAdd(&ccnt[row], 1);
                if (pos < CCAP) {
                    candV[row][pos] = z;
                    candI[row][pos] = (short)(w * 256 + t * 16 + m16);
                }
            }
        }
    __syncthreads();
    if (tid < 16 && ccnt[tid] > CCAP) ovfAny = 1;

    int prow = tid >> 4, pc = tid & 15;
    int nc = ccnt[prow];
    float tau = tau0s[prow];
    float z0 = -3.0e38f, z1 = -3.0e38f, z2 = -3.0e38f;
    if (nc <= CCAP) {
        z0 = (pc < nc)      ? candV[prow][pc]      : -3.0e38f;
        z1 = (pc + 16 < nc) ? candV[prow][pc + 16] : -3.0e38f;
        z2 = (pc + 32 < nc) ? candV[prow][pc + 32] : -3.0e38f;
        for (int it = 0; it < CCAP; it++) {
            float s = 0.f, c = 0.f;
            if (z0 > tau) { s += z0; c += 1.f; }
            if (z1 > tau) { s += z1; c += 1.f; }
            if (z2 > tau) { s += z2; c += 1.f; }
#pragma unroll
            for (int off = 8; off >= 1; off >>= 1) {
                s += __shfl_xor(s, off, 16);
                c += __shfl_xor(c, off, 16);
            }
            float tnew = (s - 1.f) / c;
            if (tnew > tau) tau = tnew; else break;
        }
    }
    if (pc == 0) taus[prow] = tau;
    if (tid < 16) scnt16[tid] = 0;
    __syncthreads();

    if (!ovfAny) {
        if (z0 > tau) {
            int sl = atomicAdd(&scnt16[prow], 1);
            if (sl < 16) { slotI[prow][sl] = candI[prow][pc]; slotV[prow][sl] = z0 - tau; }
        }
        if (z1 > tau) {
            int sl = atomicAdd(&scnt16[prow], 1);
            if (sl < 16) { slotI[prow][sl] = candI[prow][pc + 16]; slotV[prow][sl] = z1 - tau; }
        }
        if (z2 > tau) {
            int sl = atomicAdd(&scnt16[prow], 1);
            if (sl < 16) { slotI[prow][sl] = candI[prow][pc + 32]; slotV[prow][sl] = z2 - tau; }
        }
        __syncthreads();
    } else {
        for (int it = 0; it < 64; it++) {
            float s[4], c[4];
#pragma unroll
            for (int r = 0; r < 4; r++) { s[r] = 0.f; c[r] = 0.f; }
#pragma unroll
            for (int t = 0; t < 16; t++)
#pragma unroll
                for (int r = 0; r < 4; r++) {
                    float z = Cfr[t][r];
                    if (z > taus[qd * 4 + r]) { s[r] += z; c[r] += 1.f; }
                }
#pragma unroll
            for (int off = 8; off >= 1; off >>= 1)
#pragma unroll
                for (int r = 0; r < 4; r++) {
                    s[r] += __shfl_xor(s[r], off, 16);
                    c[r] += __shfl_xor(c[r], off, 16);
                }
            if (m16 == 0)
#pragma unroll
                for (int r = 0; r < 4; r++) {
                    smS[w][qd * 4 + r] = s[r];
                    smC[w][qd * 4 + r] = c[r];
                }
            __syncthreads();
            int done = 1;
            if (tid < 16) {
                float S = smS[0][tid] + smS[1][tid] + smS[2][tid] + smS[3][tid];
                float C = smC[0][tid] + smC[1][tid] + smC[2][tid] + smC[3][tid];
                float tnew = (S - 1.f) / C;
                if (C > 0.f && tnew > taus[tid]) { taus[tid] = tnew; done = 0; }
            }
            if (__syncthreads_and(done)) break;
        }
#pragma unroll
        for (int t = 0; t < 16; t++)
#pragma unroll
            for (int r = 0; r < 4; r++) {
                int row = qd * 4 + r;
                float p = Cfr[t][r] - taus[row];
                if (p > 0.f) {
                    int sl = atomicAdd(&scnt16[row], 1);
                    if (sl < 16) {
                        slotI[row][sl] = (short)(w * 256 + t * 16 + m16);
                        slotV[row][sl] = p;
                    }
                }
            }
        __syncthreads();
    }

    int nsl = min(scnt16[prow], 16);
    // ---- PV batch-gather: wide LDS reads, then all 16 V-loads independent ----
    f32x4 v0 = *(const f32x4*)&slotV[prow][0];
    f32x4 v1 = *(const f32x4*)&slotV[prow][4];
    f32x4 v2 = *(const f32x4*)&slotV[prow][8];
    f32x4 v3 = *(const f32x4*)&slotV[prow][12];
    const uint4* sIv = (const uint4*)&slotI[prow][0];
    uint4 i0 = sIv[0], i1 = sIv[1];
    float pA[16] = {v0[0], v0[1], v0[2], v0[3], v1[0], v1[1], v1[2], v1[3],
                    v2[0], v2[1], v2[2], v2[3], v3[0], v3[1], v3[2], v3[3]};
    unsigned wI[8] = {i0.x, i0.y, i0.z, i0.w, i1.x, i1.y, i1.z, i1.w};
    float4 accq = make_float4(0.f, 0.f, 0.f, 0.f);
#pragma unroll
    for (int sl = 0; sl < 16; sl++) {
        float p = (sl < nsl) ? pA[sl] : 0.f;
        int key = (int)((wI[sl >> 1] >> ((sl & 1) * 16)) & 1023u);
        float4 vv = *(const float4*)(vsh + (size_t)(kbase + key) * DH + pc * 4);
        accq.x += p * vv.x;
        accq.y += p * vv.y;
        accq.z += p * vv.z;
        accq.w += p * vv.w;
    }
    {
        unsigned short b0 = f2bf(accq.x), b1 = f2bf(accq.y), b2 = f2bf(accq.z), b3 = f2bf(accq.w);
        *(uint2*)(och + (size_t)(row0g + prow) * D_ + h * DH + pc * 4) =
            make_uint2((unsigned)b0 | ((unsigned)b1 << 16), (unsigned)b2 | ((unsigned)b3 << 16));
    }
    // ---- fused avg_attention: thread (prow, pc) accumulates slot pc of its row ----
    if (pc < nsl) {
        int key = (int)((wI[pc >> 1] >> ((pc & 1) * 16)) & 1023u);
        atomicAdd(avg + (size_t)(row0g + prow) * S_ + key, pA[pc] * 0.0625f);
    }
}

extern "C" void kernel_launch(void* const* d_in, const int* in_sizes, int n_in,
                              void* d_out, int out_size, void* d_ws, size_t ws_size,
                              hipStream_t stream) {
    const float* x  = (const float*)d_in[0];
    const float* Wq = (const float*)d_in[1];
    const float* bq = (const float*)d_in[2];
    const float* Wk = (const float*)d_in[3];
    const float* bk = (const float*)d_in[4];
    const float* Wv = (const float*)d_in[5];
    const float* bv = (const float*)d_in[6];
    const float* Wo = (const float*)d_in[7];
    const float* bo = (const float*)d_in[8];

    float* xout = (float*)d_out;                   // (B,S,D)
    float* avg  = xout + (size_t)BS * D_;          // (B,S,S)

    char* ws = (char*)d_ws;
    unsigned short* qhB  = (unsigned short*)(ws + 0);               // 8 MB
    unsigned short* qlB  = (unsigned short*)(ws + (8u << 20));      // 8 MB
    unsigned short* khB  = (unsigned short*)(ws + (16u << 20));     // 8 MB
    unsigned short* klB  = (unsigned short*)(ws + (24u << 20));     // 8 MB
    unsigned short* WqTh = (unsigned short*)(ws + (32u << 20));     // 2 MB
    unsigned short* WqTl = (unsigned short*)(ws + (34u << 20));     // 2 MB
    unsigned short* WkTh = (unsigned short*)(ws + (36u << 20));     // 2 MB
    unsigned short* WkTl = (unsigned short*)(ws + (38u << 20));     // 2 MB
    unsigned short* ochB = WqTh;                                    // alias 32..40 MB (dead after projg)
    unsigned short* WoTh = (unsigned short*)(ws + (40u << 20));     // 2 MB
    unsigned short* WvTh = (unsigned short*)(ws + (42u << 20));     // 256 KB (128x1024 bf16)
    unsigned short* WvTl = (unsigned short*)(ws + (42u << 20) + (256u << 10));  // 256 KB
    float* bvp = (float*)(ws + (42u << 20) + (512u << 10));         // 512 B
    float* vshb = (float*)(ws + (43u << 20));                       // 1 MB
    unsigned short* xhB = (unsigned short*)(ws + (44u << 20));      // 8 MB (big-ws only)
    unsigned short* xlB = (unsigned short*)(ws + (52u << 20));      // 8 MB (big-ws only)

    int bigws = ws_size >= ((size_t)60u << 20);

    prep2<<<bigws ? 9728 : 7680, 256, 0, stream>>>(Wq, Wk, Wo, Wv, bv, x,
                                                   WqTh, WqTl, WkTh, WkTl, WoTh, WvTh, WvTl,
                                                   bvp, avg, xhB, xlB);
    if (bigws) {
        projgx<<<dim3(17, 32), 256, 0, stream>>>(xhB, xlB, WqTh, WqTl, WkTh, WkTl, WvTh, WvTl,
                                                 bq, bk, bvp, qhB, qlB, khB, klB, vshb);
    } else {
        projg<<<dim3(17, 32), 256, 0, stream>>>(x, WqTh, WqTl, WkTh, WkTl, WvTh, WvTl,
                                                bq, bk, bvp, qhB, qlB, khB, klB, vshb);
    }
    attn8<<<4096, 256, 0, stream>>>(qhB, qlB, khB, klB, vshb, ochB, avg);
    outg<<<dim3(16, 64), 256, 0, stream>>>(ochB, WoTh, bo, xout);
}

// Round 9
// 335.407 us; speedup vs baseline: 2.6609x; 1.0103x over previous
//
#include <hip/hip_runtime.h>

#define B_  4
#define S_  1024
#define D_  1024
#define H_  16
#define DH  64
#define BS  4096   // B_*S_

typedef __bf16 bf16x8 __attribute__((ext_vector_type(8)));
typedef float  f32x4  __attribute__((ext_vector_type(4)));

__device__ __forceinline__ unsigned short f2bf(float f) {
    __bf16 b = (__bf16)f;
    return __builtin_bit_cast(unsigned short, b);
}
__device__ __forceinline__ float bf2f(unsigned short u) {
    return (float)__builtin_bit_cast(__bf16, u);
}
// async global->LDS, 16B/lane; LDS dest = wave-uniform base + lane*16
__device__ __forceinline__ void glds16(const void* g, void* l) {
    __builtin_amdgcn_global_load_lds((const __attribute__((address_space(1))) void*)g,
                                     (__attribute__((address_space(3))) void*)l, 16, 0, 0);
}

// ---------------- prep2: weight transp+hi/lo, Wvsh^T, bvp, avg zero, (opt) x->bf16 hilo ----------------
// grid 7680 (small-ws) or 9728 (big-ws): bid<3072 transpose, 3072..3327 Wvsh^T,
// 3328..3583 pad, 3584..7679 zero avg, 7680..9727 x conversion (big-ws only).
__global__ __launch_bounds__(256) void prep2(const float* __restrict__ Wq,
                                             const float* __restrict__ Wk,
                                             const float* __restrict__ Wo,
                                             const float* __restrict__ Wv,
                                             const float* __restrict__ bv,
                                             const float* __restrict__ x,
                                             unsigned short* __restrict__ WqTh,
                                             unsigned short* __restrict__ WqTl,
                                             unsigned short* __restrict__ WkTh,
                                             unsigned short* __restrict__ WkTl,
                                             unsigned short* __restrict__ WoTh,
                                             unsigned short* __restrict__ WvTh,
                                             unsigned short* __restrict__ WvTl,
                                             float* __restrict__ bvp,
                                             float* __restrict__ avg,
                                             unsigned short* __restrict__ xh,
                                             unsigned short* __restrict__ xl) {
    __shared__ float tile[32][33];
    int bid = blockIdx.x, tid = threadIdx.x;
    if (bid < 3072) {
        const float* W;
        unsigned short *Th, *Tl;
        int wantLo;
        if (bid < 1024)      { W = Wq; Th = WqTh; Tl = WqTl; wantLo = 1; }
        else if (bid < 2048) { W = Wk; Th = WkTh; Tl = WkTl; wantLo = 1; bid -= 1024; }
        else                 { W = Wo; Th = WoTh; Tl = nullptr; wantLo = 0; bid -= 2048; }
        int tn = bid & 31, tk = bid >> 5;
        int r = tid >> 3, c4 = (tid & 7) * 4;
        float4 v = *(const float4*)(W + (size_t)(tk * 32 + r) * D_ + tn * 32 + c4);
        tile[r][c4 + 0] = v.x;
        tile[r][c4 + 1] = v.y;
        tile[r][c4 + 2] = v.z;
        tile[r][c4 + 3] = v.w;
        __syncthreads();
        unsigned short hh[4], ll[4];
#pragma unroll
        for (int i = 0; i < 4; i++) {
            float f = tile[c4 + i][r];
            hh[i] = f2bf(f);
            ll[i] = f2bf(f - bf2f(hh[i]));
        }
        size_t off = (size_t)(tn * 32 + r) * D_ + tk * 32 + c4;
        *(uint2*)(Th + off) = make_uint2((unsigned)hh[0] | ((unsigned)hh[1] << 16),
                                         (unsigned)hh[2] | ((unsigned)hh[3] << 16));
        if (wantLo)
            *(uint2*)(Tl + off) = make_uint2((unsigned)ll[0] | ((unsigned)ll[1] << 16),
                                             (unsigned)ll[2] | ((unsigned)ll[3] << 16));
    } else if (bid < 3328) {
        // Wvsh^T rows 0..63: WvT[j][d] = mean_h Wv[d][h*64+j], hi/lo
        int e = (bid - 3072) * 256 + tid;      // 0..65535
        int d = e >> 6, j = e & 63;
        float s = 0.f;
#pragma unroll
        for (int hh = 0; hh < H_; hh++) s += Wv[(size_t)d * D_ + hh * DH + j];
        s *= (1.f / 16.f);
        unsigned short hi = f2bf(s);
        WvTh[(size_t)j * D_ + d] = hi;
        WvTl[(size_t)j * D_ + d] = f2bf(s - bf2f(hi));
        if (bid == 3072 && tid < 128) {
            float sb = 0.f;
            if (tid < 64) {
#pragma unroll
                for (int hh = 0; hh < H_; hh++) sb += bv[hh * DH + tid];
                sb *= (1.f / 16.f);
            }
            bvp[tid] = sb;
        }
    } else if (bid < 3584) {
        // zero-pad rows 64..127 of Wvsh^T
        int e = (bid - 3328) * 256 + tid;      // 0..65535
        int row = 64 + (e >> 10), col = e & 1023;
        WvTh[(size_t)row * D_ + col] = 0;
        WvTl[(size_t)row * D_ + col] = 0;
    } else if (bid < 7680) {
        // zero avg (B,S,S) = 4M floats: 4096 blocks x 256 threads x float4
        int e = (bid - 3584) * 256 + tid;      // 0..1048575
        *(float4*)(avg + (size_t)e * 4) = make_float4(0.f, 0.f, 0.f, 0.f);
    } else {
        // x -> bf16 hi/lo, 8 elems/thread: 2048 blocks x 256 threads x 8 = 4M elems
        size_t base = ((size_t)(bid - 7680) * 256 + tid) * 8;
        float4 f0 = *(const float4*)(x + base);
        float4 f1 = *(const float4*)(x + base + 4);
        float vv[8] = {f0.x, f0.y, f0.z, f0.w, f1.x, f1.y, f1.z, f1.w};
        unsigned hw[4], lw[4];
#pragma unroll
        for (int i = 0; i < 4; i++) {
            unsigned short h0 = f2bf(vv[2 * i]), h1 = f2bf(vv[2 * i + 1]);
            unsigned short l0 = f2bf(vv[2 * i] - bf2f(h0));
            unsigned short l1 = f2bf(vv[2 * i + 1] - bf2f(h1));
            hw[i] = (unsigned)h0 | ((unsigned)h1 << 16);
            lw[i] = (unsigned)l0 | ((unsigned)l1 << 16);
        }
        *(uint4*)(xh + base) = make_uint4(hw[0], hw[1], hw[2], hw[3]);
        *(uint4*)(xl + base) = make_uint4(lw[0], lw[1], lw[2], lw[3]);
    }
}

// ---------------- projg (legacy, small-ws fallback): inline x conversion ----------------
__global__ __launch_bounds__(256) void projg(const float* __restrict__ x,
                                             const unsigned short* __restrict__ WqTh, const unsigned short* __restrict__ WqTl,
                                             const unsigned short* __restrict__ WkTh, const unsigned short* __restrict__ WkTl,
                                             const unsigned short* __restrict__ WvTh, const unsigned short* __restrict__ WvTl,
                                             const float* __restrict__ bq, const float* __restrict__ bk,
                                             const float* __restrict__ bvp,
                                             unsigned short* __restrict__ qh, unsigned short* __restrict__ ql,
                                             unsigned short* __restrict__ kh, unsigned short* __restrict__ kl,
                                             float* __restrict__ vshb) {
    __shared__ unsigned short AhS[128 * 32];
    __shared__ unsigned short AlS[128 * 32];
    __shared__ unsigned short BhS[128 * 32];
    __shared__ unsigned short BlS[128 * 32];

    int tid = threadIdx.x, w = tid >> 6, lane = tid & 63;
    int m16 = lane & 15, qd = lane >> 4;
    int bn = blockIdx.x, bm = blockIdx.y;

    const unsigned short *Bh, *Bl;
    const float* bias;
    int mode;
    if (bn < 8)       { Bh = WqTh + (size_t)bn * 128 * D_;       Bl = WqTl + (size_t)bn * 128 * D_;       bias = bq + bn * 128;       mode = 0; }
    else if (bn < 16) { Bh = WkTh + (size_t)(bn - 8) * 128 * D_; Bl = WkTl + (size_t)(bn - 8) * 128 * D_; bias = bk + (bn - 8) * 128; mode = 1; }
    else              { Bh = WvTh; Bl = WvTl; bias = bvp; mode = 2; }

    int l4 = lane >> 2, c8 = (lane & 3) * 8;
    int rh = (w >> 1) * 64, chh = (w & 1) * 64;

    f32x4 acc[4][4];
#pragma unroll
    for (int it = 0; it < 4; it++)
#pragma unroll
        for (int jt = 0; jt < 4; jt++) acc[it][jt] = (f32x4){0.f, 0.f, 0.f, 0.f};

    int ra = tid >> 1, ca = (tid & 1) * 16;

    for (int k0 = 0; k0 < D_; k0 += 32) {
        const float* ax = x + (size_t)(bm * 128 + ra) * D_ + k0 + ca;
        float4 f0 = *(const float4*)(ax + 0);
        float4 f1 = *(const float4*)(ax + 4);
        float4 f2 = *(const float4*)(ax + 8);
        float4 f3 = *(const float4*)(ax + 12);
        __syncthreads();
        {
            float vv[16] = {f0.x, f0.y, f0.z, f0.w, f1.x, f1.y, f1.z, f1.w,
                            f2.x, f2.y, f2.z, f2.w, f3.x, f3.y, f3.z, f3.w};
            unsigned int hw[8], lw[8];
#pragma unroll
            for (int i = 0; i < 8; i++) {
                unsigned short h0 = f2bf(vv[2 * i]), h1 = f2bf(vv[2 * i + 1]);
                unsigned short l0 = f2bf(vv[2 * i] - bf2f(h0));
                unsigned short l1 = f2bf(vv[2 * i + 1] - bf2f(h1));
                hw[i] = (unsigned)h0 | ((unsigned)h1 << 16);
                lw[i] = (unsigned)l0 | ((unsigned)l1 << 16);
            }
            char* ah = (char*)AhS + ra * 64 + ca * 2;
            char* al = (char*)AlS + ra * 64 + ca * 2;
            *(uint4*)(ah + 0)  = make_uint4(hw[0], hw[1], hw[2], hw[3]);
            *(uint4*)(ah + 16) = make_uint4(hw[4], hw[5], hw[6], hw[7]);
            *(uint4*)(al + 0)  = make_uint4(lw[0], lw[1], lw[2], lw[3]);
            *(uint4*)(al + 16) = make_uint4(lw[4], lw[5], lw[6], lw[7]);
        }
        {
            const unsigned short* gbh = Bh + (size_t)(w * 32 + l4) * D_ + k0 + c8;
            const unsigned short* gbl = Bl + (size_t)(w * 32 + l4) * D_ + k0 + c8;
            glds16(gbh,                     (char*)BhS + w * 2048);
            glds16(gbh + (size_t)16 * D_,   (char*)BhS + w * 2048 + 1024);
            glds16(gbl,                     (char*)BlS + w * 2048);
            glds16(gbl + (size_t)16 * D_,   (char*)BlS + w * 2048 + 1024);
        }
        __syncthreads();
        bf16x8 ah[4], al[4], bh[4], bl[4];
#pragma unroll
        for (int it = 0; it < 4; it++) {
            ah[it] = *(const bf16x8*)((char*)AhS + (rh + it * 16 + m16) * 64 + qd * 16);
            al[it] = *(const bf16x8*)((char*)AlS + (rh + it * 16 + m16) * 64 + qd * 16);
        }
#pragma unroll
        for (int jt = 0; jt < 4; jt++) {
            bh[jt] = *(const bf16x8*)((char*)BhS + (chh + jt * 16 + m16) * 64 + qd * 16);
            bl[jt] = *(const bf16x8*)((char*)BlS + (chh + jt * 16 + m16) * 64 + qd * 16);
        }
#pragma unroll
        for (int it = 0; it < 4; it++)
#pragma unroll
            for (int jt = 0; jt < 4; jt++) {
                acc[it][jt] = __builtin_amdgcn_mfma_f32_16x16x32_bf16(ah[it], bh[jt], acc[it][jt], 0, 0, 0);
                acc[it][jt] = __builtin_amdgcn_mfma_f32_16x16x32_bf16(ah[it], bl[jt], acc[it][jt], 0, 0, 0);
                acc[it][jt] = __builtin_amdgcn_mfma_f32_16x16x32_bf16(al[it], bh[jt], acc[it][jt], 0, 0, 0);
            }
    }
#pragma unroll
    for (int it = 0; it < 4; it++)
#pragma unroll
        for (int jt = 0; jt < 4; jt++)
#pragma unroll
            for (int r = 0; r < 4; r++) {
                int R = bm * 128 + rh + it * 16 + qd * 4 + r;
                int c = chh + jt * 16 + m16;
                float v = acc[it][jt][r] + bias[c];
                if (mode == 0) {
                    v *= 0.125f;
                    unsigned short h0 = f2bf(v);
                    qh[(size_t)R * D_ + bn * 128 + c] = h0;
                    ql[(size_t)R * D_ + bn * 128 + c] = f2bf(v - bf2f(h0));
                } else if (mode == 1) {
                    unsigned short h0 = f2bf(v);
                    kh[(size_t)R * D_ + (bn - 8) * 128 + c] = h0;
                    kl[(size_t)R * D_ + (bn - 8) * 128 + c] = f2bf(v - bf2f(h0));
                } else {
                    if (c < 64) vshb[(size_t)R * 64 + c] = v;
                }
            }
}

// ---------------- projgx (big-ws): 64x128 tile (grid 17x64 = 4.25 blocks/CU) ----------------
// Round-9 retile: 544 blocks (2.1/CU) left every k-step's vmcnt-drain barrier exposed;
// 64-row tiles double the grid to the m97-proven ~4 blocks/CU operating point and cut
// LDS to 24KB. A staged via outg's verified 16-row/wave glds16 pattern; B unchanged.
__global__ __launch_bounds__(256) void projgx(const unsigned short* __restrict__ xh,
                                              const unsigned short* __restrict__ xl,
                                              const unsigned short* __restrict__ WqTh, const unsigned short* __restrict__ WqTl,
                                              const unsigned short* __restrict__ WkTh, const unsigned short* __restrict__ WkTl,
                                              const unsigned short* __restrict__ WvTh, const unsigned short* __restrict__ WvTl,
                                              const float* __restrict__ bq, const float* __restrict__ bk,
                                              const float* __restrict__ bvp,
                                              unsigned short* __restrict__ qh, unsigned short* __restrict__ ql,
                                              unsigned short* __restrict__ kh, unsigned short* __restrict__ kl,
                                              float* __restrict__ vshb) {
    __shared__ unsigned short AhS[64 * 32];
    __shared__ unsigned short AlS[64 * 32];
    __shared__ unsigned short BhS[128 * 32];
    __shared__ unsigned short BlS[128 * 32];

    int tid = threadIdx.x, w = tid >> 6, lane = tid & 63;
    int m16 = lane & 15, qd = lane >> 4;
    int bn = blockIdx.x, bm = blockIdx.y;

    const unsigned short *Bh, *Bl;
    const float* bias;
    int mode;
    if (bn < 8)       { Bh = WqTh + (size_t)bn * 128 * D_;       Bl = WqTl + (size_t)bn * 128 * D_;       bias = bq + bn * 128;       mode = 0; }
    else if (bn < 16) { Bh = WkTh + (size_t)(bn - 8) * 128 * D_; Bl = WkTl + (size_t)(bn - 8) * 128 * D_; bias = bk + (bn - 8) * 128; mode = 1; }
    else              { Bh = WvTh; Bl = WvTl; bias = bvp; mode = 2; }

    int l4 = lane >> 2, c8 = (lane & 3) * 8;
    int rh = (w >> 1) * 32, chh = (w & 1) * 64;   // wave quadrant: 32 rows x 64 cols

    f32x4 acc[2][4];
#pragma unroll
    for (int it = 0; it < 2; it++)
#pragma unroll
        for (int jt = 0; jt < 4; jt++) acc[it][jt] = (f32x4){0.f, 0.f, 0.f, 0.f};

    for (int k0 = 0; k0 < D_; k0 += 32) {
        __syncthreads();   // prior iteration's LDS reads complete before overwrite
        {
            // A: 64 rows, wave w stages rows w*16..w*16+15 (1 glds16 hi + 1 lo)
            const unsigned short* gah = xh + (size_t)(bm * 64 + w * 16 + l4) * D_ + k0 + c8;
            const unsigned short* gal = xl + (size_t)(bm * 64 + w * 16 + l4) * D_ + k0 + c8;
            glds16(gah, (char*)AhS + w * 1024);
            glds16(gal, (char*)AlS + w * 1024);
            // B: 128 rows, wave w stages rows w*32..w*32+31 (2 glds16 hi + 2 lo)
            const unsigned short* gbh = Bh + (size_t)(w * 32 + l4) * D_ + k0 + c8;
            const unsigned short* gbl = Bl + (size_t)(w * 32 + l4) * D_ + k0 + c8;
            glds16(gbh,                     (char*)BhS + w * 2048);
            glds16(gbh + (size_t)16 * D_,   (char*)BhS + w * 2048 + 1024);
            glds16(gbl,                     (char*)BlS + w * 2048);
            glds16(gbl + (size_t)16 * D_,   (char*)BlS + w * 2048 + 1024);
        }
        __syncthreads();   // barrier drains vmcnt (compiler-inserted) -> staged data visible
        bf16x8 ah[2], al[2], bh[4], bl[4];
#pragma unroll
        for (int it = 0; it < 2; it++) {
            ah[it] = *(const bf16x8*)((char*)AhS + (rh + it * 16 + m16) * 64 + qd * 16);
            al[it] = *(const bf16x8*)((char*)AlS + (rh + it * 16 + m16) * 64 + qd * 16);
        }
#pragma unroll
        for (int jt = 0; jt < 4; jt++) {
            bh[jt] = *(const bf16x8*)((char*)BhS + (chh + jt * 16 + m16) * 64 + qd * 16);
            bl[jt] = *(const bf16x8*)((char*)BlS + (chh + jt * 16 + m16) * 64 + qd * 16);
        }
#pragma unroll
        for (int it = 0; it < 2; it++)
#pragma unroll
            for (int jt = 0; jt < 4; jt++) {
                acc[it][jt] = __builtin_amdgcn_mfma_f32_16x16x32_bf16(ah[it], bh[jt], acc[it][jt], 0, 0, 0);
                acc[it][jt] = __builtin_amdgcn_mfma_f32_16x16x32_bf16(ah[it], bl[jt], acc[it][jt], 0, 0, 0);
                acc[it][jt] = __builtin_amdgcn_mfma_f32_16x16x32_bf16(al[it], bh[jt], acc[it][jt], 0, 0, 0);
            }
    }
#pragma unroll
    for (int it = 0; it < 2; it++)
#pragma unroll
        for (int jt = 0; jt < 4; jt++)
#pragma unroll
            for (int r = 0; r < 4; r++) {
                int R = bm * 64 + rh + it * 16 + qd * 4 + r;
                int c = chh + jt * 16 + m16;
                float v = acc[it][jt][r] + bias[c];
                if (mode == 0) {
                    v *= 0.125f;
                    unsigned short h0 = f2bf(v);
                    qh[(size_t)R * D_ + bn * 128 + c] = h0;
                    ql[(size_t)R * D_ + bn * 128 + c] = f2bf(v - bf2f(h0));
                } else if (mode == 1) {
                    unsigned short h0 = f2bf(v);
                    kh[(size_t)R * D_ + (bn - 8) * 128 + c] = h0;
                    kl[(size_t)R * D_ + (bn - 8) * 128 + c] = f2bf(v - bf2f(h0));
                } else {
                    if (c < 64) vshb[(size_t)R * 64 + c] = v;
                }
            }
}

// ---------------- outg: x_out = och @ Wo + bo, 64x64 tile (4 blocks/CU), bf16 single, all glds ----------------
__global__ __launch_bounds__(256) void outg(const unsigned short* __restrict__ A,
                                            const unsigned short* __restrict__ Bh,
                                            const float* __restrict__ bias,
                                            float* __restrict__ C) {
    __shared__ unsigned short AhS[64 * 32];
    __shared__ unsigned short BhS[64 * 32];

    int tid = threadIdx.x, w = tid >> 6, lane = tid & 63;
    int m16 = lane & 15, qd = lane >> 4;
    int bn = blockIdx.x, bm = blockIdx.y;
    int l4 = lane >> 2, c8 = (lane & 3) * 8;
    int rh = (w >> 1) * 32, chh = (w & 1) * 32;

    f32x4 acc[2][2];
#pragma unroll
    for (int it = 0; it < 2; it++)
#pragma unroll
        for (int jt = 0; jt < 2; jt++) acc[it][jt] = (f32x4){0.f, 0.f, 0.f, 0.f};

    for (int k0 = 0; k0 < D_; k0 += 32) {
        __syncthreads();
        {
            const unsigned short* ga = A + (size_t)(bm * 64 + w * 16 + l4) * D_ + k0 + c8;
            glds16(ga, (char*)AhS + w * 1024);
            const unsigned short* gb = Bh + (size_t)(bn * 64 + w * 16 + l4) * D_ + k0 + c8;
            glds16(gb, (char*)BhS + w * 1024);
        }
        __syncthreads();
        bf16x8 ah[2], bh[2];
#pragma unroll
        for (int it = 0; it < 2; it++)
            ah[it] = *(const bf16x8*)((char*)AhS + (rh + it * 16 + m16) * 64 + qd * 16);
#pragma unroll
        for (int jt = 0; jt < 2; jt++)
            bh[jt] = *(const bf16x8*)((char*)BhS + (chh + jt * 16 + m16) * 64 + qd * 16);
#pragma unroll
        for (int it = 0; it < 2; it++)
#pragma unroll
            for (int jt = 0; jt < 2; jt++)
                acc[it][jt] = __builtin_amdgcn_mfma_f32_16x16x32_bf16(ah[it], bh[jt], acc[it][jt], 0, 0, 0);
    }
#pragma unroll
    for (int it = 0; it < 2; it++)
#pragma unroll
        for (int jt = 0; jt < 2; jt++)
#pragma unroll
            for (int r = 0; r < 4; r++) {
                int R = bm * 64 + rh + it * 16 + qd * 4 + r;
                int cc = bn * 64 + chh + jt * 16 + m16;
                C[(size_t)R * D_ + cc] = acc[it][jt][r] + bias[cc];
            }
}

// ---------------- fused attention v15: v14 + max folded into QK loop (bit-identical) ----------------
#define CCAP 48
__global__ __launch_bounds__(256, 4) void attn8(const unsigned short* __restrict__ qh,
                                                const unsigned short* __restrict__ ql,
                                                const unsigned short* __restrict__ kh,
                                                const unsigned short* __restrict__ kl,
                                                const float* __restrict__ vsh,
                                                unsigned short* __restrict__ och,
                                                float* __restrict__ avg) {
    // K staging: wave w owns KST + w*8192, two 4KB buffers (hi 2KB @ +0, lo 2KB @ +2048).
    __shared__ __align__(16) char KST[32768];
    __shared__ float smM[4][16];
    __shared__ float smS[4][16], smC[4][16];
    __shared__ float tau0s[16];
    __shared__ float taus[16];
    __shared__ int   ccnt[16];
    __shared__ int   ovfAny;
    __shared__ int   scnt16[16];

    // aliased into KST (first touched strictly after the post-QK barrier)
    float (*candV)[CCAP] = (float (*)[CCAP])(KST);          // 3072 B
    short (*candI)[CCAP] = (short (*)[CCAP])(KST + 3072);   // 1536 B
    float (*slotV)[16]   = (float (*)[16])(KST + 4608);     // 1024 B
    short (*slotI)[16]   = (short (*)[16])(KST + 5632);     //  512 B

    int tid = threadIdx.x, w = tid >> 6, lane = tid & 63;
    int m16 = lane & 15, qd = lane >> 4;

    // qt-major decode: same-XCD consecutive blocks share (bb,h), walk qt.
    int bid = blockIdx.x;
    int xcd = bid & 7;
    int j   = bid >> 3;                 // 0..511
    int bh  = ((j >> 6) << 3) | xcd;    // 0..63
    int qt  = j & 63;
    int bb  = bh >> 4, h = bh & 15;
    int row0g = bb * S_ + qt * 16;
    int kbase = bb * S_;

    // Q fragments (direct global, once)
    bf16x8 aH[2], aL[2];
#pragma unroll
    for (int c = 0; c < 2; c++) {
        size_t off = (size_t)(row0g + m16) * D_ + h * DH + c * 32 + qd * 8;
        aH[c] = *(const bf16x8*)(qh + off);
        aL[c] = *(const bf16x8*)(ql + off);
    }

    f32x4 Cfr[16];
#pragma unroll
    for (int t = 0; t < 16; t++) Cfr[t] = (f32x4){0.f, 0.f, 0.f, 0.f};

    float mxr[4];
#pragma unroll
    for (int r = 0; r < 4; r++) mxr[r] = -3.0e38f;

    // staging source: lane l covers row (l>>3), swizzled chunk (l&7)^(l>>3)
    char* myK = KST + w * 8192;
    {
        int sr = lane >> 3;
        int sc = (lane & 7) ^ sr;
        const unsigned short* ksh = kh + (size_t)(kbase + w * 256 + sr) * D_ + h * DH + sc * 8;
        const unsigned short* ksl = kl + (size_t)(kbase + w * 256 + sr) * D_ + h * DH + sc * 8;

#define STAGE_K(t, buf) do {                                        \
        size_t o_ = (size_t)(t) * 16 * D_;                          \
        char* db_ = myK + (buf) * 4096;                             \
        glds16(ksh + o_,                  db_);                     \
        glds16(ksh + o_ + (size_t)8 * D_, db_ + 1024);              \
        glds16(ksl + o_,                  db_ + 2048);              \
        glds16(ksl + o_ + (size_t)8 * D_, db_ + 3072);              \
    } while (0)

        // fragment read offsets (swizzled): chunk c*4+qd, row m16
        int sw0 = m16 * 128 + (((qd    ) ^ (m16 & 7)) << 4);
        int sw1 = m16 * 128 + (((4 + qd) ^ (m16 & 7)) << 4);

        STAGE_K(0, 0);
        asm volatile("s_waitcnt vmcnt(0)" ::: "memory");   // drains Q loads + tile 0
        __builtin_amdgcn_sched_barrier(0);

#pragma unroll
        for (int t = 0; t < 16; t++) {
            if (t < 15) {
                STAGE_K(t + 1, (t + 1) & 1);
                asm volatile("s_waitcnt vmcnt(4)" ::: "memory");   // tile t done, t+1 in flight
            } else {
                asm volatile("s_waitcnt vmcnt(0)" ::: "memory");
            }
            __builtin_amdgcn_sched_barrier(0);
            const char* tbuf = myK + (t & 1) * 4096;
            bf16x8 bfh0 = *(const bf16x8*)(tbuf + sw0);
            bf16x8 bfh1 = *(const bf16x8*)(tbuf + sw1);
            bf16x8 bfl0 = *(const bf16x8*)(tbuf + 2048 + sw0);
            bf16x8 bfl1 = *(const bf16x8*)(tbuf + 2048 + sw1);
            f32x4 a = Cfr[t];
            __builtin_amdgcn_s_setprio(1);
            a = __builtin_amdgcn_mfma_f32_16x16x32_bf16(aH[0], bfh0, a, 0, 0, 0);
            a = __builtin_amdgcn_mfma_f32_16x16x32_bf16(aH[1], bfh1, a, 0, 0, 0);
            a = __builtin_amdgcn_mfma_f32_16x16x32_bf16(aH[0], bfl0, a, 0, 0, 0);
            a = __builtin_amdgcn_mfma_f32_16x16x32_bf16(aH[1], bfl1, a, 0, 0, 0);
            a = __builtin_amdgcn_mfma_f32_16x16x32_bf16(aL[0], bfh0, a, 0, 0, 0);
            a = __builtin_amdgcn_mfma_f32_16x16x32_bf16(aL[1], bfh1, a, 0, 0, 0);
            __builtin_amdgcn_s_setprio(0);
            // fold row-max here while a is in VGPRs (saves a full Cfr re-read pass)
#pragma unroll
            for (int r = 0; r < 4; r++) mxr[r] = fmaxf(mxr[r], a[r]);
            Cfr[t] = a;
        }
#undef STAGE_K
    }

#pragma unroll
    for (int off = 8; off >= 1; off >>= 1)
#pragma unroll
        for (int r = 0; r < 4; r++) mxr[r] = fmaxf(mxr[r], __shfl_xor(mxr[r], off, 16));
    if (m16 == 0)
#pragma unroll
        for (int r = 0; r < 4; r++) smM[w][qd * 4 + r] = mxr[r];
    if (tid < 16) ccnt[tid] = 0;
    if (tid == 0) ovfAny = 0;
    __syncthreads();
    if (tid < 16)
        tau0s[tid] = fmaxf(fmaxf(smM[0][tid], smM[1][tid]), fmaxf(smM[2][tid], smM[3][tid])) - 1.0f;
    __syncthreads();

    float t0r[4];
#pragma unroll
    for (int r = 0; r < 4; r++) t0r[r] = tau0s[qd * 4 + r];

#pragma unroll
    for (int t = 0; t < 16; t++)
#pragma unroll
        for (int r = 0; r < 4; r++) {
            float z = Cfr[t][r];
            int row = qd * 4 + r;
            if (z > t0r[r]) {
                int pos = atomicAdd(&ccnt[row], 1);
                if (pos < CCAP) {
                    candV[row][pos] = z;
                    candI[row][pos] = (short)(w * 256 + t * 16 + m16);
                }
            }
        }
    __syncthreads();
    if (tid < 16 && ccnt[tid] > CCAP) ovfAny = 1;

    int prow = tid >> 4, pc = tid & 15;
    int nc = ccnt[prow];
    float tau = tau0s[prow];
    float z0 = -3.0e38f, z1 = -3.0e38f, z2 = -3.0e38f;
    if (nc <= CCAP) {
        z0 = (pc < nc)      ? candV[prow][pc]      : -3.0e38f;
        z1 = (pc + 16 < nc) ? candV[prow][pc + 16] : -3.0e38f;
        z2 = (pc + 32 < nc) ? candV[prow][pc + 32] : -3.0e38f;
        for (int it = 0; it < CCAP; it++) {
            float s = 0.f, c = 0.f;
            if (z0 > tau) { s += z0; c += 1.f; }
            if (z1 > tau) { s += z1; c += 1.f; }
            if (z2 > tau) { s += z2; c += 1.f; }
#pragma unroll
            for (int off = 8; off >= 1; off >>= 1) {
                s += __shfl_xor(s, off, 16);
                c += __shfl_xor(c, off, 16);
            }
            float tnew = (s - 1.f) / c;
            if (tnew > tau) tau = tnew; else break;
        }
    }
    if (pc == 0) taus[prow] = tau;
    if (tid < 16) scnt16[tid] = 0;
    __syncthreads();

    if (!ovfAny) {
        if (z0 > tau) {
            int sl = atomicAdd(&scnt16[prow], 1);
            if (sl < 16) { slotI[prow][sl] = candI[prow][pc]; slotV[prow][sl] = z0 - tau; }
        }
        if (z1 > tau) {
            int sl = atomicAdd(&scnt16[prow], 1);
            if (sl < 16) { slotI[prow][sl] = candI[prow][pc + 16]; slotV[prow][sl] = z1 - tau; }
        }
        if (z2 > tau) {
            int sl = atomicAdd(&scnt16[prow], 1);
            if (sl < 16) { slotI[prow][sl] = candI[prow][pc + 32]; slotV[prow][sl] = z2 - tau; }
        }
        __syncthreads();
    } else {
        for (int it = 0; it < 64; it++) {
            float s[4], c[4];
#pragma unroll
            for (int r = 0; r < 4; r++) { s[r] = 0.f; c[r] = 0.f; }
#pragma unroll
            for (int t = 0; t < 16; t++)
#pragma unroll
                for (int r = 0; r < 4; r++) {
                    float z = Cfr[t][r];
                    if (z > taus[qd * 4 + r]) { s[r] += z; c[r] += 1.f; }
                }
#pragma unroll
            for (int off = 8; off >= 1; off >>= 1)
#pragma unroll
                for (int r = 0; r < 4; r++) {
                    s[r] += __shfl_xor(s[r], off, 16);
                    c[r] += __shfl_xor(c[r], off, 16);
                }
            if (m16 == 0)
#pragma unroll
                for (int r = 0; r < 4; r++) {
                    smS[w][qd * 4 + r] = s[r];
                    smC[w][qd * 4 + r] = c[r];
                }
            __syncthreads();
            int done = 1;
            if (tid < 16) {
                float S = smS[0][tid] + smS[1][tid] + smS[2][tid] + smS[3][tid];
                float C = smC[0][tid] + smC[1][tid] + smC[2][tid] + smC[3][tid];
                float tnew = (S - 1.f) / C;
                if (C > 0.f && tnew > taus[tid]) { taus[tid] = tnew; done = 0; }
            }
            if (__syncthreads_and(done)) break;
        }
#pragma unroll
        for (int t = 0; t < 16; t++)
#pragma unroll
            for (int r = 0; r < 4; r++) {
                int row = qd * 4 + r;
                float p = Cfr[t][r] - taus[row];
                if (p > 0.f) {
                    int sl = atomicAdd(&scnt16[row], 1);
                    if (sl < 16) {
                        slotI[row][sl] = (short)(w * 256 + t * 16 + m16);
                        slotV[row][sl] = p;
                    }
                }
            }
        __syncthreads();
    }

    int nsl = min(scnt16[prow], 16);
    // ---- PV batch-gather: wide LDS reads, then all 16 V-loads independent ----
    f32x4 v0 = *(const f32x4*)&slotV[prow][0];
    f32x4 v1 = *(const f32x4*)&slotV[prow][4];
    f32x4 v2 = *(const f32x4*)&slotV[prow][8];
    f32x4 v3 = *(const f32x4*)&slotV[prow][12];
    const uint4* sIv = (const uint4*)&slotI[prow][0];
    uint4 i0 = sIv[0], i1 = sIv[1];
    float pA[16] = {v0[0], v0[1], v0[2], v0[3], v1[0], v1[1], v1[2], v1[3],
                    v2[0], v2[1], v2[2], v2[3], v3[0], v3[1], v3[2], v3[3]};
    unsigned wI[8] = {i0.x, i0.y, i0.z, i0.w, i1.x, i1.y, i1.z, i1.w};
    float4 accq = make_float4(0.f, 0.f, 0.f, 0.f);
#pragma unroll
    for (int sl = 0; sl < 16; sl++) {
        float p = (sl < nsl) ? pA[sl] : 0.f;
        int key = (int)((wI[sl >> 1] >> ((sl & 1) * 16)) & 1023u);
        float4 vv = *(const float4*)(vsh + (size_t)(kbase + key) * DH + pc * 4);
        accq.x += p * vv.x;
        accq.y += p * vv.y;
        accq.z += p * vv.z;
        accq.w += p * vv.w;
    }
    {
        unsigned short b0 = f2bf(accq.x), b1 = f2bf(accq.y), b2 = f2bf(accq.z), b3 = f2bf(accq.w);
        *(uint2*)(och + (size_t)(row0g + prow) * D_ + h * DH + pc * 4) =
            make_uint2((unsigned)b0 | ((unsigned)b1 << 16), (unsigned)b2 | ((unsigned)b3 << 16));
    }
    // ---- fused avg_attention: thread (prow, pc) accumulates slot pc of its row ----
    if (pc < nsl) {
        int key = (int)((wI[pc >> 1] >> ((pc & 1) * 16)) & 1023u);
        atomicAdd(avg + (size_t)(row0g + prow) * S_ + key, pA[pc] * 0.0625f);
    }
}

extern "C" void kernel_launch(void* const* d_in, const int* in_sizes, int n_in,
                              void* d_out, int out_size, void* d_ws, size_t ws_size,
                              hipStream_t stream) {
    const float* x  = (const float*)d_in[0];
    const float* Wq = (const float*)d_in[1];
    const float* bq = (const float*)d_in[2];
    const float* Wk = (const float*)d_in[3];
    const float* bk = (const float*)d_in[4];
    const float* Wv = (const float*)d_in[5];
    const float* bv = (const float*)d_in[6];
    const float* Wo = (const float*)d_in[7];
    const float* bo = (const float*)d_in[8];

    float* xout = (float*)d_out;                   // (B,S,D)
    float* avg  = xout + (size_t)BS * D_;          // (B,S,S)

    char* ws = (char*)d_ws;
    unsigned short* qhB  = (unsigned short*)(ws + 0);               // 8 MB
    unsigned short* qlB  = (unsigned short*)(ws + (8u << 20));      // 8 MB
    unsigned short* khB  = (unsigned short*)(ws + (16u << 20));     // 8 MB
    unsigned short* klB  = (unsigned short*)(ws + (24u << 20));     // 8 MB
    unsigned short* WqTh = (unsigned short*)(ws + (32u << 20));     // 2 MB
    unsigned short* WqTl = (unsigned short*)(ws + (34u << 20));     // 2 MB
    unsigned short* WkTh = (unsigned short*)(ws + (36u << 20));     // 2 MB
    unsigned short* WkTl = (unsigned short*)(ws + (38u << 20));     // 2 MB
    unsigned short* ochB = WqTh;                                    // alias 32..40 MB (dead after projg)
    unsigned short* WoTh = (unsigned short*)(ws + (40u << 20));     // 2 MB
    unsigned short* WvTh = (unsigned short*)(ws + (42u << 20));     // 256 KB (128x1024 bf16)
    unsigned short* WvTl = (unsigned short*)(ws + (42u << 20) + (256u << 10));  // 256 KB
    float* bvp = (float*)(ws + (42u << 20) + (512u << 10));         // 512 B
    float* vshb = (float*)(ws + (43u << 20));                       // 1 MB
    unsigned short* xhB = (unsigned short*)(ws + (44u << 20));      // 8 MB (big-ws only)
    unsigned short* xlB = (unsigned short*)(ws + (52u << 20));      // 8 MB (big-ws only)

    int bigws = ws_size >= ((size_t)60u << 20);

    prep2<<<bigws ? 9728 : 7680, 256, 0, stream>>>(Wq, Wk, Wo, Wv, bv, x,
                                                   WqTh, WqTl, WkTh, WkTl, WoTh, WvTh, WvTl,
                                                   bvp, avg, xhB, xlB);
    if (bigws) {
        projgx<<<dim3(17, 64), 256, 0, stream>>>(xhB, xlB, WqTh, WqTl, WkTh, WkTl, WvTh, WvTl,
                                                 bq, bk, bvp, qhB, qlB, khB, klB, vshb);
    } else {
        projg<<<dim3(17, 32), 256, 0, stream>>>(x, WqTh, WqTl, WkTh, WkTl, WvTh, WvTl,
                                                bq, bk, bvp, qhB, qlB, khB, klB, vshb);
    }
    attn8<<<4096, 256, 0, stream>>>(qhB, qlB, khB, klB, vshb, ochB, avg);
    outg<<<dim3(16, 64), 256, 0, stream>>>(ochB, WoTh, bo, xout);
}